// Round 1
// baseline (18285.471 us; speedup 1.0000x reference)
//
#include <hip/hip_runtime.h>

#define B_ 4
#define S_ 2048
#define H_ 1024
#define NH_ 16
#define HS_ 64

typedef __bf16 bf16x8 __attribute__((ext_vector_type(8)));
typedef __bf16 bf16x4 __attribute__((ext_vector_type(4)));
typedef float  f32x4  __attribute__((ext_vector_type(4)));

// ---------------- fp32 -> bf16 conversion (vectorized) ----------------
__global__ void cvt_f32_bf16(const float* __restrict__ in, __bf16* __restrict__ out, int n4) {
    int i = blockIdx.x * blockDim.x + threadIdx.x;
    if (i >= n4) return;
    float4 v = reinterpret_cast<const float4*>(in)[i];
    bf16x4 o;
    o[0] = (__bf16)v.x; o[1] = (__bf16)v.y; o[2] = (__bf16)v.z; o[3] = (__bf16)v.w;
    reinterpret_cast<bf16x4*>(out)[i] = o;
}

// ---------------- bf16 MFMA GEMM:  Y[m,n] = sum_k A[m,k] * W[n,k] + bias[n] ----------------
// LDS-free: 64x64 block tile, 4 waves (2x2), each wave 32x32 via 2x2 mfma_f32_16x16x32_bf16.
// A fragment: row = lane&15, k = (lane>>4)*8 + j   (16B contiguous per lane)
// B fragment: col = lane&15, k = (lane>>4)*8 + j   (W is row-major [N][K] -> K-contiguous, same pattern)
// D fragment: row = (lane>>4)*4 + r, col = lane&15
__device__ __forceinline__ void store_tile(const f32x4& acc, int mbase, int nbase, int lane,
                                           const float* __restrict__ bias, void* __restrict__ out,
                                           int N, int out_f32) {
    const int r16 = lane & 15, kg = lane >> 4;
    const int col = nbase + r16;
    const float bv = bias[col];
#pragma unroll
    for (int r = 0; r < 4; ++r) {
        const int row = mbase + kg * 4 + r;
        const float v = acc[r] + bv;
        if (out_f32) ((float*)out)[(long)row * N + col] = v;
        else         ((__bf16*)out)[(long)row * N + col] = (__bf16)v;
    }
}

__global__ __launch_bounds__(256) void gemm_bf16_nt(
    const __bf16* __restrict__ A, const __bf16* __restrict__ W,
    const float* __restrict__ bias, void* __restrict__ out,
    int M, int N, int K, int out_f32)
{
    const int lane = threadIdx.x & 63;
    const int w    = threadIdx.x >> 6;
    const int wr = w >> 1, wc = w & 1;
    const int m0 = blockIdx.y * 64 + wr * 32;
    const int n0 = blockIdx.x * 64 + wc * 32;
    const int r16 = lane & 15;
    const int kof = (lane >> 4) * 8;

    const __bf16* a0p = A + (long)(m0 +      r16) * K + kof;
    const __bf16* a1p = A + (long)(m0 + 16 + r16) * K + kof;
    const __bf16* b0p = W + (long)(n0 +      r16) * K + kof;
    const __bf16* b1p = W + (long)(n0 + 16 + r16) * K + kof;

    f32x4 acc00 = {0.f,0.f,0.f,0.f}, acc01 = {0.f,0.f,0.f,0.f};
    f32x4 acc10 = {0.f,0.f,0.f,0.f}, acc11 = {0.f,0.f,0.f,0.f};

#pragma unroll 2
    for (int k0 = 0; k0 < K; k0 += 32) {
        bf16x8 a0 = *reinterpret_cast<const bf16x8*>(a0p + k0);
        bf16x8 a1 = *reinterpret_cast<const bf16x8*>(a1p + k0);
        bf16x8 b0 = *reinterpret_cast<const bf16x8*>(b0p + k0);
        bf16x8 b1 = *reinterpret_cast<const bf16x8*>(b1p + k0);
        acc00 = __builtin_amdgcn_mfma_f32_16x16x32_bf16(a0, b0, acc00, 0, 0, 0);
        acc01 = __builtin_amdgcn_mfma_f32_16x16x32_bf16(a0, b1, acc01, 0, 0, 0);
        acc10 = __builtin_amdgcn_mfma_f32_16x16x32_bf16(a1, b0, acc10, 0, 0, 0);
        acc11 = __builtin_amdgcn_mfma_f32_16x16x32_bf16(a1, b1, acc11, 0, 0, 0);
    }

    store_tile(acc00, m0,      n0,      lane, bias, out, N, out_f32);
    store_tile(acc01, m0,      n0 + 16, lane, bias, out, N, out_f32);
    store_tile(acc10, m0 + 16, n0,      lane, bias, out, N, out_f32);
    store_tile(acc11, m0 + 16, n0 + 16, lane, bias, out, N, out_f32);
}

// ---------------- causal flash attention, wave = 8 query rows, lane = head-dim ----------------
// Q/K/V stored [B,S,H] bf16 (head h occupies cols h*64..h*64+63). Output written same layout
// (== attn.swapaxes(1,2).reshape(B,S,H)).
__global__ __launch_bounds__(256) void attn_flash(
    const __bf16* __restrict__ Q, const __bf16* __restrict__ Kb,
    const __bf16* __restrict__ V, __bf16* __restrict__ O)
{
    const int lane = threadIdx.x & 63;
    const int gw = blockIdx.x * 4 + (threadIdx.x >> 6);  // global wave id
    const int nqb = S_ / 8;                              // 256 query-blocks per head
    const int qb = gw % nqb;
    const int h  = (gw / nqb) % NH_;
    const int b  = gw / (nqb * NH_);
    const int q0 = qb * 8;
    const long base = ((long)b * S_) * H_ + h * HS_ + lane;

    float q[8], m[8], l[8], o[8];
#pragma unroll
    for (int r = 0; r < 8; ++r) {
        q[r] = 0.125f * (float)Q[base + (long)(q0 + r) * H_];  // scale = 1/sqrt(64)
        m[r] = -3.0e38f; l[r] = 0.f; o[r] = 0.f;
    }

    const int kvend = q0 + 8;
    for (int kv = 0; kv < kvend; ++kv) {
        const float kf = (float)Kb[base + (long)kv * H_];
        const float vf = (float)V [base + (long)kv * H_];
#pragma unroll
        for (int r = 0; r < 8; ++r) {
            float p = q[r] * kf;
            p += __shfl_xor(p, 32); p += __shfl_xor(p, 16); p += __shfl_xor(p, 8);
            p += __shfl_xor(p, 4);  p += __shfl_xor(p, 2);  p += __shfl_xor(p, 1);
            if (kv <= q0 + r) {   // wave-uniform branch
                const float mn = fmaxf(m[r], p);
                const float f  = __expf(m[r] - mn);
                const float e  = __expf(p - mn);
                l[r] = l[r] * f + e;
                o[r] = o[r] * f + e * vf;
                m[r] = mn;
            }
        }
    }
#pragma unroll
    for (int r = 0; r < 8; ++r)
        O[base + (long)(q0 + r) * H_] = (__bf16)(o[r] / l[r]);
}

// ---------------- launch ----------------
extern "C" void kernel_launch(void* const* d_in, const int* in_sizes, int n_in,
                              void* d_out, int out_size, void* d_ws, size_t ws_size,
                              hipStream_t stream) {
    const float* x  = (const float*)d_in[0];
    const float* Wq = (const float*)d_in[1];
    const float* bq = (const float*)d_in[2];
    const float* Wk = (const float*)d_in[3];
    const float* bk = (const float*)d_in[4];
    const float* Wv = (const float*)d_in[5];
    const float* bv = (const float*)d_in[6];
    const float* Wp = (const float*)d_in[7];
    const float* bp = (const float*)d_in[8];
    float* out = (float*)d_out;

    const int M = B_ * S_;     // 8192
    const int N = H_;          // 1024
    const int K = H_;          // 1024

    char* ws = (char*)d_ws;
    size_t off = 0;
    __bf16* xb  = (__bf16*)(ws + off); off += (size_t)M * K * 2;        // 16 MB
    __bf16* Wqb = (__bf16*)(ws + off); off += (size_t)N * K * 2;        // 2 MB
    __bf16* Wkb = (__bf16*)(ws + off); off += (size_t)N * K * 2;
    __bf16* Wvb = (__bf16*)(ws + off); off += (size_t)N * K * 2;
    __bf16* Wpb = (__bf16*)(ws + off); off += (size_t)N * K * 2;
    __bf16* Qb  = (__bf16*)(ws + off); off += (size_t)M * H_ * 2;       // 16 MB
    __bf16* Kbf = (__bf16*)(ws + off); off += (size_t)M * H_ * 2;
    __bf16* Vb  = (__bf16*)(ws + off); off += (size_t)M * H_ * 2;
    __bf16* Ab  = (__bf16*)(ws + off); off += (size_t)M * H_ * 2;       // attention out

    // convert inputs to bf16
    {
        int n4 = M * K / 4;
        cvt_f32_bf16<<<(n4 + 255) / 256, 256, 0, stream>>>(x, xb, n4);
        int w4 = N * K / 4;
        cvt_f32_bf16<<<(w4 + 255) / 256, 256, 0, stream>>>(Wq, Wqb, w4);
        cvt_f32_bf16<<<(w4 + 255) / 256, 256, 0, stream>>>(Wk, Wkb, w4);
        cvt_f32_bf16<<<(w4 + 255) / 256, 256, 0, stream>>>(Wv, Wvb, w4);
        cvt_f32_bf16<<<(w4 + 255) / 256, 256, 0, stream>>>(Wp, Wpb, w4);
    }

    dim3 gg(N / 64, M / 64);
    gemm_bf16_nt<<<gg, 256, 0, stream>>>(xb, Wqb, bq, Qb,  M, N, K, 0);
    gemm_bf16_nt<<<gg, 256, 0, stream>>>(xb, Wkb, bk, Kbf, M, N, K, 0);
    gemm_bf16_nt<<<gg, 256, 0, stream>>>(xb, Wvb, bv, Vb,  M, N, K, 0);

    // attention: one wave per 8 query rows; 4 waves per block
    {
        int total_waves = B_ * NH_ * (S_ / 8);   // 16384
        attn_flash<<<total_waves / 4, 256, 0, stream>>>(Qb, Kbf, Vb, Ab);
    }

    // output projection -> fp32 d_out
    gemm_bf16_nt<<<gg, 256, 0, stream>>>(Ab, Wpb, bp, out, M, N, K, 1);
}

// Round 2
// 1237.756 us; speedup vs baseline: 14.7731x; 14.7731x over previous
//
#include <hip/hip_runtime.h>

#define B_ 4
#define S_ 2048
#define H_ 1024
#define NH_ 16
#define HS_ 64
#define SG_ (B_*S_)   // 8192 total sequence rows

typedef __bf16 bf16x8 __attribute__((ext_vector_type(8)));
typedef __bf16 bf16x4 __attribute__((ext_vector_type(4)));
typedef float  f32x4  __attribute__((ext_vector_type(4)));

// ---------------- fp32 -> bf16 conversion ----------------
__global__ void cvt_f32_bf16(const float* __restrict__ in, __bf16* __restrict__ out, int n4) {
    int i = blockIdx.x * blockDim.x + threadIdx.x;
    if (i >= n4) return;
    float4 v = reinterpret_cast<const float4*>(in)[i];
    bf16x4 o;
    o[0] = (__bf16)v.x; o[1] = (__bf16)v.y; o[2] = (__bf16)v.z; o[3] = (__bf16)v.w;
    reinterpret_cast<bf16x4*>(out)[i] = o;
}

// ---------------- bf16 MFMA GEMM:  Y[m,n] = sum_k A[m,k] * W[n,k] + bias ----------------
// bias_row=0: bias indexed by n (torch Linear). bias_row=1: bias indexed by m (for V^T = Wv x^T).
__device__ __forceinline__ void store_tile(const f32x4& acc, int mbase, int nbase, int lane,
                                           const float* __restrict__ bias, void* __restrict__ out,
                                           long N, int out_f32, int bias_row) {
    const int r16 = lane & 15, kg = lane >> 4;
    const int col = nbase + r16;
    const float bc = bias_row ? 0.f : bias[col];
#pragma unroll
    for (int r = 0; r < 4; ++r) {
        const int row = mbase + kg * 4 + r;
        const float v = acc[r] + (bias_row ? bias[row] : bc);
        if (out_f32) ((float*)out)[(long)row * N + col] = v;
        else         ((__bf16*)out)[(long)row * N + col] = (__bf16)v;
    }
}

__global__ __launch_bounds__(256) void gemm_bf16_nt(
    const __bf16* __restrict__ A, const __bf16* __restrict__ W,
    const float* __restrict__ bias, void* __restrict__ out,
    int M, int N, int K, int out_f32, int bias_row)
{
    const int lane = threadIdx.x & 63;
    const int w    = threadIdx.x >> 6;
    const int wr = w >> 1, wc = w & 1;
    const int m0 = blockIdx.y * 64 + wr * 32;
    const int n0 = blockIdx.x * 64 + wc * 32;
    const int r16 = lane & 15;
    const int kof = (lane >> 4) * 8;

    const __bf16* a0p = A + (long)(m0 +      r16) * K + kof;
    const __bf16* a1p = A + (long)(m0 + 16 + r16) * K + kof;
    const __bf16* b0p = W + (long)(n0 +      r16) * K + kof;
    const __bf16* b1p = W + (long)(n0 + 16 + r16) * K + kof;

    f32x4 acc00 = {0.f,0.f,0.f,0.f}, acc01 = {0.f,0.f,0.f,0.f};
    f32x4 acc10 = {0.f,0.f,0.f,0.f}, acc11 = {0.f,0.f,0.f,0.f};

#pragma unroll 2
    for (int k0 = 0; k0 < K; k0 += 32) {
        bf16x8 a0 = *reinterpret_cast<const bf16x8*>(a0p + k0);
        bf16x8 a1 = *reinterpret_cast<const bf16x8*>(a1p + k0);
        bf16x8 b0 = *reinterpret_cast<const bf16x8*>(b0p + k0);
        bf16x8 b1 = *reinterpret_cast<const bf16x8*>(b1p + k0);
        acc00 = __builtin_amdgcn_mfma_f32_16x16x32_bf16(a0, b0, acc00, 0, 0, 0);
        acc01 = __builtin_amdgcn_mfma_f32_16x16x32_bf16(a0, b1, acc01, 0, 0, 0);
        acc10 = __builtin_amdgcn_mfma_f32_16x16x32_bf16(a1, b0, acc10, 0, 0, 0);
        acc11 = __builtin_amdgcn_mfma_f32_16x16x32_bf16(a1, b1, acc11, 0, 0, 0);
    }

    store_tile(acc00, m0,      n0,      lane, bias, out, N, out_f32, bias_row);
    store_tile(acc01, m0,      n0 + 16, lane, bias, out, N, out_f32, bias_row);
    store_tile(acc10, m0 + 16, n0,      lane, bias, out, N, out_f32, bias_row);
    store_tile(acc11, m0 + 16, n0 + 16, lane, bias, out, N, out_f32, bias_row);
}

// ---------------- MFMA causal flash attention ----------------
// One wave per 16 query rows (one (b,h)). KV tiles of 32.
// S^T = mfma(A=K, B=Q): D row = kv_local = g*4+r (+16 for subtile 1), col = q = c.
// Each lane holds 8 P values of ONE q row -> softmax = in-lane + shfl_xor(16/32).
// PV: O^T = mfma(A=V^T, B=P^T). V^T rows loaded in permuted order
// kv = kt0 + 4g + (j&3) + 16*(j>>2) so the S^T registers ARE the B fragment (no shuffles).
__global__ __launch_bounds__(256) void attn_mfma(
    const __bf16* __restrict__ Q, const __bf16* __restrict__ Kb,
    const __bf16* __restrict__ Vt, __bf16* __restrict__ Ab)
{
    __shared__ __bf16 lds_o[4][16 * 72];
    const int lane = threadIdx.x & 63;
    const int widx = threadIdx.x >> 6;
    const int c = lane & 15, g = lane >> 4;
    const int gw = blockIdx.x * 4 + widx;
    const int qt = gw & 127;            // 128 q-tiles per head
    const int bh = gw >> 7;
    const int b = bh >> 4, h = bh & 15;
    const int q0 = qt * 16;

    // Q fragments (16 rows x 64 dim), pre-scaled by 1/sqrt(64)=0.125 (exact in bf16)
    const long qbase = ((long)(b * S_ + q0 + c)) * H_ + h * HS_ + g * 8;
    bf16x8 qf0 = *reinterpret_cast<const bf16x8*>(Q + qbase);
    bf16x8 qf1 = *reinterpret_cast<const bf16x8*>(Q + qbase + 32);
#pragma unroll
    for (int j = 0; j < 8; ++j) {
        qf0[j] = (__bf16)(0.125f * (float)qf0[j]);
        qf1[j] = (__bf16)(0.125f * (float)qf1[j]);
    }

    f32x4 ot[4] = {{0,0,0,0},{0,0,0,0},{0,0,0,0},{0,0,0,0}};  // O^T, 4 d-blocks
    float m = -1e30f, l = 0.f;

    const long kbase = ((long)(b * S_ + c)) * H_ + h * HS_ + g * 8;
    const long vbase = ((long)(h * HS_ + c)) * SG_ + b * S_ + g * 4;

    for (int kt0 = 0; kt0 < q0 + 16; kt0 += 32) {
        // K fragments: rows kv = kt0 + st*16 + c, dims half*32 + g*8..+7
        const long kb = kbase + (long)kt0 * H_;
        bf16x8 k00 = *reinterpret_cast<const bf16x8*>(Kb + kb);
        bf16x8 k01 = *reinterpret_cast<const bf16x8*>(Kb + kb + 32);
        bf16x8 k10 = *reinterpret_cast<const bf16x8*>(Kb + kb + (long)16 * H_);
        bf16x8 k11 = *reinterpret_cast<const bf16x8*>(Kb + kb + (long)16 * H_ + 32);

        // V^T fragments (permuted kv order), issued early to overlap with softmax
        bf16x8 vf[4];
#pragma unroll
        for (int blk = 0; blk < 4; ++blk) {
            const __bf16* vp = Vt + vbase + (long)(blk * 16) * SG_ + kt0;
            bf16x4 lo = *reinterpret_cast<const bf16x4*>(vp);
            bf16x4 hi = *reinterpret_cast<const bf16x4*>(vp + 16);
            vf[blk][0] = lo[0]; vf[blk][1] = lo[1]; vf[blk][2] = lo[2]; vf[blk][3] = lo[3];
            vf[blk][4] = hi[0]; vf[blk][5] = hi[1]; vf[blk][6] = hi[2]; vf[blk][7] = hi[3];
        }

        // S^T tiles
        f32x4 s0 = {0,0,0,0}, s1 = {0,0,0,0};
        s0 = __builtin_amdgcn_mfma_f32_16x16x32_bf16(k00, qf0, s0, 0, 0, 0);
        s0 = __builtin_amdgcn_mfma_f32_16x16x32_bf16(k01, qf1, s0, 0, 0, 0);
        s1 = __builtin_amdgcn_mfma_f32_16x16x32_bf16(k10, qf0, s1, 0, 0, 0);
        s1 = __builtin_amdgcn_mfma_f32_16x16x32_bf16(k11, qf1, s1, 0, 0, 0);

        // causal mask (wave-uniform branch: only diagonal tiles)
        if (kt0 + 31 > q0) {
            const int qg = q0 + c;
#pragma unroll
            for (int r = 0; r < 4; ++r) {
                if (kt0 + g * 4 + r      > qg) s0[r] = -1e30f;
                if (kt0 + 16 + g * 4 + r > qg) s1[r] = -1e30f;
            }
        }

        // online softmax: row = q = c (replicated across g groups)
        float pm = fmaxf(fmaxf(fmaxf(s0[0], s0[1]), fmaxf(s0[2], s0[3])),
                         fmaxf(fmaxf(s1[0], s1[1]), fmaxf(s1[2], s1[3])));
        pm = fmaxf(pm, __shfl_xor(pm, 16));
        pm = fmaxf(pm, __shfl_xor(pm, 32));
        const float mn = fmaxf(m, pm);
        const float f = __expf(m - mn);
        m = mn;

        float p[8];
#pragma unroll
        for (int r = 0; r < 4; ++r) {
            p[r]     = __expf(s0[r] - mn);
            p[4 + r] = __expf(s1[r] - mn);
        }
        float rs = ((p[0] + p[1]) + (p[2] + p[3])) + ((p[4] + p[5]) + (p[6] + p[7]));
        rs += __shfl_xor(rs, 16);
        rs += __shfl_xor(rs, 32);
        l = l * f + rs;

        // P -> bf16 B-fragment (register order already matches via kv permutation)
        bf16x8 pf;
#pragma unroll
        for (int j = 0; j < 8; ++j) pf[j] = (__bf16)p[j];

#pragma unroll
        for (int blk = 0; blk < 4; ++blk) {
            ot[blk] = ot[blk] * f;
            ot[blk] = __builtin_amdgcn_mfma_f32_16x16x32_bf16(vf[blk], pf, ot[blk], 0, 0, 0);
        }
    }

    // epilogue: O^T (row d = blk*16+g*4+r, col q = c) -> LDS -> coalesced O store
    const float invl = 1.0f / l;
    __bf16* myo = lds_o[widx];
#pragma unroll
    for (int blk = 0; blk < 4; ++blk) {
        bf16x4 t;
#pragma unroll
        for (int r = 0; r < 4; ++r) t[r] = (__bf16)(ot[blk][r] * invl);
        *reinterpret_cast<bf16x4*>(myo + c * 72 + blk * 16 + g * 4) = t;
    }
    __syncthreads();
    const int qr = lane >> 2, dc = (lane & 3) * 16;
    const __bf16* src = myo + qr * 72 + dc;
    bf16x8 r0 = *reinterpret_cast<const bf16x8*>(src);
    bf16x8 r1 = *reinterpret_cast<const bf16x8*>(src + 8);
    __bf16* dst = Ab + ((long)(b * S_ + q0 + qr)) * H_ + h * HS_ + dc;
    *reinterpret_cast<bf16x8*>(dst) = r0;
    *reinterpret_cast<bf16x8*>(dst + 8) = r1;
}

// ---------------- launch ----------------
extern "C" void kernel_launch(void* const* d_in, const int* in_sizes, int n_in,
                              void* d_out, int out_size, void* d_ws, size_t ws_size,
                              hipStream_t stream) {
    const float* x  = (const float*)d_in[0];
    const float* Wq = (const float*)d_in[1];
    const float* bq = (const float*)d_in[2];
    const float* Wk = (const float*)d_in[3];
    const float* bk = (const float*)d_in[4];
    const float* Wv = (const float*)d_in[5];
    const float* bv = (const float*)d_in[6];
    const float* Wp = (const float*)d_in[7];
    const float* bp = (const float*)d_in[8];
    float* out = (float*)d_out;

    const int M = SG_;         // 8192
    const int N = H_;          // 1024
    const int K = H_;          // 1024

    char* ws = (char*)d_ws;
    size_t off = 0;
    __bf16* xb  = (__bf16*)(ws + off); off += (size_t)M * K * 2;        // 16 MB
    __bf16* Wqb = (__bf16*)(ws + off); off += (size_t)N * K * 2;        // 2 MB
    __bf16* Wkb = (__bf16*)(ws + off); off += (size_t)N * K * 2;
    __bf16* Wvb = (__bf16*)(ws + off); off += (size_t)N * K * 2;
    __bf16* Wpb = (__bf16*)(ws + off); off += (size_t)N * K * 2;
    __bf16* Qb  = (__bf16*)(ws + off); off += (size_t)M * H_ * 2;       // 16 MB
    __bf16* Kbf = (__bf16*)(ws + off); off += (size_t)M * H_ * 2;
    __bf16* Vt  = (__bf16*)(ws + off); off += (size_t)M * H_ * 2;       // V^T [1024][8192]
    __bf16* Ab  = (__bf16*)(ws + off); off += (size_t)M * H_ * 2;       // attention out

    // convert inputs to bf16
    {
        int n4 = M * K / 4;
        cvt_f32_bf16<<<(n4 + 255) / 256, 256, 0, stream>>>(x, xb, n4);
        int w4 = N * K / 4;
        cvt_f32_bf16<<<(w4 + 255) / 256, 256, 0, stream>>>(Wq, Wqb, w4);
        cvt_f32_bf16<<<(w4 + 255) / 256, 256, 0, stream>>>(Wk, Wkb, w4);
        cvt_f32_bf16<<<(w4 + 255) / 256, 256, 0, stream>>>(Wv, Wvb, w4);
        cvt_f32_bf16<<<(w4 + 255) / 256, 256, 0, stream>>>(Wp, Wpb, w4);
    }

    dim3 gg(N / 64, M / 64);
    gemm_bf16_nt<<<gg, 256, 0, stream>>>(xb, Wqb, bq, Qb,  M, N, K, 0, 0);
    gemm_bf16_nt<<<gg, 256, 0, stream>>>(xb, Wkb, bk, Kbf, M, N, K, 0, 0);
    // V projection computed transposed: V^T[f][sg] = Wv[f] . x[sg] + bv[f]
    dim3 gv(M / 64, N / 64);
    gemm_bf16_nt<<<gv, 256, 0, stream>>>(Wvb, xb, bv, Vt, N, M, K, 0, 1);

    // attention: 8192 waves (64 bh x 128 q-tiles), 4 waves/block
    attn_mfma<<<2048, 256, 0, stream>>>(Qb, Kbf, Vt, Ab);

    // output projection -> fp32 d_out
    gemm_bf16_nt<<<gg, 256, 0, stream>>>(Ab, Wpb, bp, out, M, N, K, 1, 0);
}

// Round 5
// 338.130 us; speedup vs baseline: 54.0782x; 3.6606x over previous
//
#include <hip/hip_runtime.h>

#define B_ 4
#define S_ 2048
#define H_ 1024
#define NH_ 16
#define HS_ 64
#define SG_ (B_*S_)   // 8192 total sequence rows

typedef __bf16 bf16x8 __attribute__((ext_vector_type(8)));
typedef __bf16 bf16x4 __attribute__((ext_vector_type(4)));
typedef float  f32x4  __attribute__((ext_vector_type(4)));

// async global->LDS, 16B per lane. dest = wave-uniform base (lane*16 auto-appended).
__device__ __forceinline__ void gload16(const void* g, void* l) {
    __builtin_amdgcn_global_load_lds(
        (const __attribute__((address_space(1))) void*)g,
        (__attribute__((address_space(3))) void*)l,
        16, 0, 0);
}

// ---------------- fp32 -> bf16 conversion ----------------
__global__ void cvt_f32_bf16(const float* __restrict__ in, __bf16* __restrict__ out, int n4) {
    int i = blockIdx.x * blockDim.x + threadIdx.x;
    if (i >= n4) return;
    float4 v = reinterpret_cast<const float4*>(in)[i];
    bf16x4 o;
    o[0] = (__bf16)v.x; o[1] = (__bf16)v.y; o[2] = (__bf16)v.z; o[3] = (__bf16)v.w;
    reinterpret_cast<bf16x4*>(out)[i] = o;
}

// ---------------- 128x128 MFMA GEMM (m97 structure):  Y[m,n] = A[m,:].W[n,:] + bias ----------------
// LDS tiles [128][32] bf16 with 16B-chunk XOR swizzle (chunk ^= row&3), staged by global_load_lds
// from pre-swizzled global addresses. 4 waves (2x2), each 64x64 = 4x4 mfma_16x16x32.
__device__ __forceinline__ void store_tile(const f32x4& acc, long mbase, long nbase, int lane,
                                           const float* __restrict__ bias, void* __restrict__ out,
                                           long N, int out_f32, int bias_row) {
    const int r16 = lane & 15, kg = lane >> 4;
    const long col = nbase + r16;
    const float bc = bias_row ? 0.f : bias[col];
#pragma unroll
    for (int r = 0; r < 4; ++r) {
        const long row = mbase + kg * 4 + r;
        const float v = acc[r] + (bias_row ? bias[row] : bc);
        if (out_f32) ((float*)out)[row * N + col] = v;
        else         ((__bf16*)out)[row * N + col] = (__bf16)v;
    }
}

__global__ __launch_bounds__(256) void gemm128(
    const __bf16* __restrict__ A, const __bf16* __restrict__ W,
    const float* __restrict__ bias, void* __restrict__ out,
    int M, int N, int K, int out_f32, int bias_row)
{
    __shared__ __bf16 sA[128][32];
    __shared__ __bf16 sB[128][32];
    const int lane = threadIdx.x & 63, widx = threadIdx.x >> 6;
    const int wr = widx >> 1, wc = widx & 1;
    const int c = lane & 15, g = lane >> 4;
    const long m0 = (long)blockIdx.y * 128, n0 = (long)blockIdx.x * 128;
    const int srow = lane >> 2;       // 0..15 (staging row within 16-row group)
    const int schunk = lane & 3;      // 16B chunk within 64B row

    f32x4 acc[4][4] = {};

    for (int k0 = 0; k0 < K; k0 += 32) {
#pragma unroll
        for (int it = 0; it < 2; ++it) {
            const int row = widx * 32 + it * 16 + srow;
            gload16(A + (m0 + row) * K + k0 + ((schunk ^ (row & 3)) << 3),
                    &sA[widx * 32 + it * 16][0]);
        }
#pragma unroll
        for (int it = 0; it < 2; ++it) {
            const int row = widx * 32 + it * 16 + srow;
            gload16(W + (n0 + row) * K + k0 + ((schunk ^ (row & 3)) << 3),
                    &sB[widx * 32 + it * 16][0]);
        }
        __syncthreads();
        bf16x8 af[4], bfr[4];
#pragma unroll
        for (int i = 0; i < 4; ++i) {
            const int ra = wr * 64 + i * 16 + c;
            af[i]  = *(const bf16x8*)((const char*)&sA[ra][0] + ((g ^ (ra & 3)) << 4));
            const int rb = wc * 64 + i * 16 + c;
            bfr[i] = *(const bf16x8*)((const char*)&sB[rb][0] + ((g ^ (rb & 3)) << 4));
        }
#pragma unroll
        for (int i = 0; i < 4; ++i)
#pragma unroll
            for (int j = 0; j < 4; ++j)
                acc[i][j] = __builtin_amdgcn_mfma_f32_16x16x32_bf16(af[i], bfr[j], acc[i][j], 0, 0, 0);
        __syncthreads();
    }

#pragma unroll
    for (int i = 0; i < 4; ++i)
#pragma unroll
        for (int j = 0; j < 4; ++j)
            store_tile(acc[i][j], m0 + wr * 64 + i * 16, n0 + wc * 64 + j * 16,
                       lane, bias, out, N, out_f32, bias_row);
}

// ---------------- MFMA causal flash attention, block-shared LDS K/V ----------------
// Block = 128 q rows of one (b,h); 4 waves x 32 q rows. KV tiles of 64 staged in LDS.
// S^T = mfma(A=K, B=Q); softmax in-register (lane holds full row slice for q=c);
// PV via permuted-kv V^T fragments (registers of S^T ARE the B fragment).
__global__ __launch_bounds__(256) void attn_mfma2(
    const __bf16* __restrict__ Q, const __bf16* __restrict__ Kg,
    const __bf16* __restrict__ Vt, __bf16* __restrict__ Ab)
{
    __shared__ __bf16 ldsK[64][64];    // [kv][d], 16B chunks XOR-swizzled by kv&7
    __shared__ __bf16 ldsV[64][64];    // [d][kv], 16B chunks XOR-swizzled by d&7
    __shared__ __bf16 ldsE[4][32 * 72];

    const int lane = threadIdx.x & 63, widx = threadIdx.x >> 6;
    const int c = lane & 15, g = lane >> 4;
    const int bid = blockIdx.x;
    const int bh = bid & 63, chunk = bid >> 6;   // chunk-major => same head -> same XCD residue
    const int b = bh >> 4, h = bh & 15;
    const int q0 = chunk * 128;
    const int q0w = q0 + widx * 32;

    // Q fragments [qi 0/1 = 16-row frags][hf 0/1 = k halves], pre-scaled by 1/8
    bf16x8 qf[2][2];
#pragma unroll
    for (int qi = 0; qi < 2; ++qi)
#pragma unroll
        for (int hf = 0; hf < 2; ++hf) {
            const long qa = ((long)(b * S_ + q0w + qi * 16 + c)) * H_ + h * HS_ + hf * 32 + g * 8;
            bf16x8 t = *reinterpret_cast<const bf16x8*>(Q + qa);
#pragma unroll
            for (int j = 0; j < 8; ++j) t[j] = (__bf16)(0.125f * (float)t[j]);
            qf[qi][hf] = t;
        }

    f32x4 ot[4][2] = {};               // O^T accum [dblk][qfrag]
    float m[2] = {-1e30f, -1e30f}, l[2] = {0.f, 0.f};

    const int nt = 2 * (chunk + 1);
    const int sr8 = lane >> 3;         // staging row-in-8 group
    const int sc8 = lane & 7;          // staging 16B chunk (8 per 128B row)

    for (int t = 0; t < nt; ++t) {
        const int kt = t * 64;
        // ---- stage K tile rows widx*16..+15 (2 instrs), V^T tile d rows same ----
#pragma unroll
        for (int it = 0; it < 2; ++it) {
            const int row = widx * 16 + it * 8 + sr8;
            gload16(Kg + ((long)(b * S_ + kt + row)) * H_ + h * HS_ + ((sc8 ^ (row & 7)) << 3),
                    &ldsK[widx * 16 + it * 8][0]);
        }
#pragma unroll
        for (int it = 0; it < 2; ++it) {
            const int dr = widx * 16 + it * 8 + sr8;
            gload16(Vt + ((long)(h * HS_ + dr)) * SG_ + b * S_ + kt + ((sc8 ^ (dr & 7)) << 3),
                    &ldsV[widx * 16 + it * 8][0]);
        }
        __syncthreads();

        if (kt <= q0w + 31) {          // wave-uniform: wave has unmasked rows in this tile
            // ---- QK^T: 4 kv-subtiles x 2 qfrags ----
            f32x4 st[4][2] = {};
#pragma unroll
            for (int t4 = 0; t4 < 4; ++t4) {
                const int r = t4 * 16 + c;
                const char* kp = (const char*)&ldsK[r][0];
                bf16x8 kf0 = *(const bf16x8*)(kp + (((g)     ^ (c & 7)) << 4));
                bf16x8 kf1 = *(const bf16x8*)(kp + (((4 | g) ^ (c & 7)) << 4));
#pragma unroll
                for (int qi = 0; qi < 2; ++qi) {
                    st[t4][qi] = __builtin_amdgcn_mfma_f32_16x16x32_bf16(kf0, qf[qi][0], st[t4][qi], 0, 0, 0);
                    st[t4][qi] = __builtin_amdgcn_mfma_f32_16x16x32_bf16(kf1, qf[qi][1], st[t4][qi], 0, 0, 0);
                }
            }
            // ---- causal mask (diagonal tiles only) ----
            if (kt + 63 > q0w) {
#pragma unroll
                for (int t4 = 0; t4 < 4; ++t4)
#pragma unroll
                    for (int qi = 0; qi < 2; ++qi)
#pragma unroll
                        for (int r = 0; r < 4; ++r)
                            if (kt + t4 * 16 + g * 4 + r > q0w + qi * 16 + c)
                                st[t4][qi][r] = -1e30f;
            }
            // ---- online softmax + PV ----
            bf16x8 pf[2][2];
            float fr[2];
#pragma unroll
            for (int qi = 0; qi < 2; ++qi) {
                float pm = -1e30f;
#pragma unroll
                for (int t4 = 0; t4 < 4; ++t4)
#pragma unroll
                    for (int r = 0; r < 4; ++r) pm = fmaxf(pm, st[t4][qi][r]);
                pm = fmaxf(pm, __shfl_xor(pm, 16));
                pm = fmaxf(pm, __shfl_xor(pm, 32));
                const float mn = fmaxf(m[qi], pm);
                fr[qi] = __expf(m[qi] - mn);
                m[qi] = mn;
                float p[16], rs = 0.f;
#pragma unroll
                for (int t4 = 0; t4 < 4; ++t4)
#pragma unroll
                    for (int r = 0; r < 4; ++r) {
                        const float e = __expf(st[t4][qi][r] - mn);
                        p[t4 * 4 + r] = e; rs += e;
                    }
                rs += __shfl_xor(rs, 16);
                rs += __shfl_xor(rs, 32);
                l[qi] = l[qi] * fr[qi] + rs;
#pragma unroll
                for (int j = 0; j < 8; ++j) {
                    pf[0][qi][j] = (__bf16)p[j];
                    pf[1][qi][j] = (__bf16)p[8 + j];
                }
            }
#pragma unroll
            for (int blk = 0; blk < 4; ++blk) {
#pragma unroll
                for (int qi = 0; qi < 2; ++qi) ot[blk][qi] *= fr[qi];
                const char* vp = (const char*)&ldsV[blk * 16 + c][0];
                const int sw = c & 7;
#pragma unroll
                for (int hf = 0; hf < 2; ++hf) {
                    bf16x4 lo = *(const bf16x4*)(vp + ((((hf << 2) + (g >> 1))     ^ sw) << 4) + ((g & 1) << 3));
                    bf16x4 hi = *(const bf16x4*)(vp + ((((hf << 2) + 2 + (g >> 1)) ^ sw) << 4) + ((g & 1) << 3));
                    bf16x8 vf;
                    vf[0] = lo[0]; vf[1] = lo[1]; vf[2] = lo[2]; vf[3] = lo[3];
                    vf[4] = hi[0]; vf[5] = hi[1]; vf[6] = hi[2]; vf[7] = hi[3];
#pragma unroll
                    for (int qi = 0; qi < 2; ++qi)
                        ot[blk][qi] = __builtin_amdgcn_mfma_f32_16x16x32_bf16(vf, pf[hf][qi], ot[blk][qi], 0, 0, 0);
                }
            }
        }
        __syncthreads();
    }

    // ---- epilogue: O^T -> LDS transpose -> coalesced store ----
    __bf16* myo = ldsE[widx];
#pragma unroll
    for (int qi = 0; qi < 2; ++qi) {
        const float invl = 1.0f / l[qi];
#pragma unroll
        for (int blk = 0; blk < 4; ++blk) {
            bf16x4 tv;
#pragma unroll
            for (int r = 0; r < 4; ++r) tv[r] = (__bf16)(ot[blk][qi][r] * invl);
            *reinterpret_cast<bf16x4*>(myo + (qi * 16 + c) * 72 + blk * 16 + g * 4) = tv;
        }
    }
#pragma unroll
    for (int half = 0; half < 2; ++half) {
        const int qr = lane >> 2, dc = (lane & 3) * 16;
        const __bf16* src = myo + (half * 16 + qr) * 72 + dc;
        bf16x8 r0 = *reinterpret_cast<const bf16x8*>(src);
        bf16x8 r1 = *reinterpret_cast<const bf16x8*>(src + 8);
        __bf16* dst = Ab + ((long)(b * S_ + q0w + half * 16 + qr)) * H_ + h * HS_ + dc;
        *reinterpret_cast<bf16x8*>(dst) = r0;
        *reinterpret_cast<bf16x8*>(dst + 8) = r1;
    }
}

// ---------------- launch ----------------
extern "C" void kernel_launch(void* const* d_in, const int* in_sizes, int n_in,
                              void* d_out, int out_size, void* d_ws, size_t ws_size,
                              hipStream_t stream) {
    const float* x  = (const float*)d_in[0];
    const float* Wq = (const float*)d_in[1];
    const float* bq = (const float*)d_in[2];
    const float* Wk = (const float*)d_in[3];
    const float* bk = (const float*)d_in[4];
    const float* Wv = (const float*)d_in[5];
    const float* bv = (const float*)d_in[6];
    const float* Wp = (const float*)d_in[7];
    const float* bp = (const float*)d_in[8];
    float* out = (float*)d_out;

    const int M = SG_;         // 8192
    const int N = H_;          // 1024
    const int K = H_;          // 1024

    char* ws = (char*)d_ws;
    size_t off = 0;
    __bf16* xb  = (__bf16*)(ws + off); off += (size_t)M * K * 2;
    __bf16* Wqb = (__bf16*)(ws + off); off += (size_t)N * K * 2;
    __bf16* Wkb = (__bf16*)(ws + off); off += (size_t)N * K * 2;
    __bf16* Wvb = (__bf16*)(ws + off); off += (size_t)N * K * 2;
    __bf16* Wpb = (__bf16*)(ws + off); off += (size_t)N * K * 2;
    __bf16* Qb  = (__bf16*)(ws + off); off += (size_t)M * H_ * 2;
    __bf16* Kbf = (__bf16*)(ws + off); off += (size_t)M * H_ * 2;
    __bf16* Vt  = (__bf16*)(ws + off); off += (size_t)M * H_ * 2;   // V^T [1024][8192]
    __bf16* Ab  = (__bf16*)(ws + off); off += (size_t)M * H_ * 2;

    {
        int n4 = M * K / 4;
        cvt_f32_bf16<<<(n4 + 255) / 256, 256, 0, stream>>>(x, xb, n4);
        int w4 = N * K / 4;
        cvt_f32_bf16<<<(w4 + 255) / 256, 256, 0, stream>>>(Wq, Wqb, w4);
        cvt_f32_bf16<<<(w4 + 255) / 256, 256, 0, stream>>>(Wk, Wkb, w4);
        cvt_f32_bf16<<<(w4 + 255) / 256, 256, 0, stream>>>(Wv, Wvb, w4);
        cvt_f32_bf16<<<(w4 + 255) / 256, 256, 0, stream>>>(Wp, Wpb, w4);
    }

    dim3 gg(N / 128, M / 128);
    gemm128<<<gg, 256, 0, stream>>>(xb, Wqb, bq, Qb,  M, N, K, 0, 0);
    gemm128<<<gg, 256, 0, stream>>>(xb, Wkb, bk, Kbf, M, N, K, 0, 0);
    // V projection computed transposed: V^T[f][sg] = Wv[f] . x[sg] + bv[f]
    dim3 gv(M / 128, N / 128);
    gemm128<<<gv, 256, 0, stream>>>(Wvb, xb, bv, Vt, N, M, K, 0, 1);

    // attention: 1024 blocks (16 q-chunks x 64 bh), 4 waves/block
    attn_mfma2<<<16 * 64, 256, 0, stream>>>(Qb, Kbf, Vt, Ab);

    // output projection -> fp32 d_out
    gemm128<<<gg, 256, 0, stream>>>(Ab, Wpb, bp, out, M, N, K, 1, 0);
}

// Round 8
// 314.591 us; speedup vs baseline: 58.1245x; 1.0748x over previous
//
#include <hip/hip_runtime.h>

#define B_ 4
#define S_ 2048
#define H_ 1024
#define NH_ 16
#define HS_ 64
#define SG_ (B_*S_)   // 8192 total sequence rows

typedef __bf16 bf16x8 __attribute__((ext_vector_type(8)));
typedef __bf16 bf16x4 __attribute__((ext_vector_type(4)));
typedef float  f32x4  __attribute__((ext_vector_type(4)));

// async global->LDS, 16B per lane. dest = wave-uniform base (lane*16 auto-appended).
__device__ __forceinline__ void gload16(const void* g, void* l) {
    __builtin_amdgcn_global_load_lds(
        (const __attribute__((address_space(1))) void*)g,
        (__attribute__((address_space(3))) void*)l,
        16, 0, 0);
}

// ---------------- fp32 -> bf16 conversion ----------------
__global__ void cvt_f32_bf16(const float* __restrict__ in, __bf16* __restrict__ out, int n4) {
    int i = blockIdx.x * blockDim.x + threadIdx.x;
    if (i >= n4) return;
    float4 v = reinterpret_cast<const float4*>(in)[i];
    bf16x4 o;
    o[0] = (__bf16)v.x; o[1] = (__bf16)v.y; o[2] = (__bf16)v.z; o[3] = (__bf16)v.w;
    reinterpret_cast<bf16x4*>(out)[i] = o;
}

// fused convert of the 4 weight matrices (one launch instead of four)
__global__ void cvt_w4(const float* __restrict__ w0, const float* __restrict__ w1,
                       const float* __restrict__ w2, const float* __restrict__ w3,
                       __bf16* __restrict__ o0, __bf16* __restrict__ o1,
                       __bf16* __restrict__ o2, __bf16* __restrict__ o3, int n4) {
    int i = blockIdx.x * blockDim.x + threadIdx.x;
    if (i >= n4) return;
    const float* in; __bf16* out;
    switch (blockIdx.y) {
        case 0: in = w0; out = o0; break;
        case 1: in = w1; out = o1; break;
        case 2: in = w2; out = o2; break;
        default: in = w3; out = o3; break;
    }
    float4 v = reinterpret_cast<const float4*>(in)[i];
    bf16x4 o;
    o[0] = (__bf16)v.x; o[1] = (__bf16)v.y; o[2] = (__bf16)v.z; o[3] = (__bf16)v.w;
    reinterpret_cast<bf16x4*>(out)[i] = o;
}

// ---------------- 128x128 MFMA GEMM, BK=64:  Y[m,n] = A[m,:].W[n,:] + bias ----------------
// LDS tiles [128][64] bf16, 16B chunks XOR-swizzled by row&7 (both sides), staged by
// global_load_lds from pre-swizzled global addresses. 4 waves (2x2), each 64x64.
// BK=64 halves barrier count vs BK=32 (barrier drain is the known ~20% stall).
__device__ __forceinline__ void store_tile(const f32x4& acc, long mbase, long nbase, int lane,
                                           const float* __restrict__ bias, void* __restrict__ out,
                                           long N, int out_f32, int bias_row) {
    const int r16 = lane & 15, kg = lane >> 4;
    const long col = nbase + r16;
    const float bc = bias_row ? 0.f : bias[col];
#pragma unroll
    for (int r = 0; r < 4; ++r) {
        const long row = mbase + kg * 4 + r;
        const float v = acc[r] + (bias_row ? bias[row] : bc);
        if (out_f32) ((float*)out)[row * N + col] = v;
        else         ((__bf16*)out)[row * N + col] = (__bf16)v;
    }
}

__global__ __launch_bounds__(256) void gemm128(
    const __bf16* __restrict__ A, const __bf16* __restrict__ W,
    const float* __restrict__ bias, void* __restrict__ out,
    int M, int N, int K, int out_f32, int bias_row)
{
    __shared__ __bf16 sA[128][64];
    __shared__ __bf16 sB[128][64];
    const int lane = threadIdx.x & 63, widx = threadIdx.x >> 6;
    const int wr = widx >> 1, wc = widx & 1;
    const int c = lane & 15, g = lane >> 4;
    const long m0 = (long)blockIdx.y * 128, n0 = (long)blockIdx.x * 128;
    const int sr8 = lane >> 3;        // staging row within 8-row group
    const int sc8 = lane & 7;         // staging 16B chunk (8 per 128B row)

    f32x4 acc[4][4] = {};

    for (int k0 = 0; k0 < K; k0 += 64) {
#pragma unroll
        for (int it = 0; it < 4; ++it) {
            const int rb = it * 32 + widx * 8;
            const int row = rb + sr8;
            gload16(A + (m0 + row) * K + k0 + ((sc8 ^ (row & 7)) << 3), &sA[rb][0]);
            gload16(W + (n0 + row) * K + k0 + ((sc8 ^ (row & 7)) << 3), &sB[rb][0]);
        }
        __syncthreads();
        bf16x8 af[2][4], bfr[2][4];
#pragma unroll
        for (int i = 0; i < 4; ++i) {
            const int ra = wr * 64 + i * 16 + c;
            const char* ap = (const char*)&sA[ra][0];
            af[0][i] = *(const bf16x8*)(ap + ((( g    ) ^ (ra & 7)) << 4));
            af[1][i] = *(const bf16x8*)(ap + (((4 | g) ^ (ra & 7)) << 4));
            const int rbn = wc * 64 + i * 16 + c;
            const char* bp = (const char*)&sB[rbn][0];
            bfr[0][i] = *(const bf16x8*)(bp + ((( g    ) ^ (rbn & 7)) << 4));
            bfr[1][i] = *(const bf16x8*)(bp + (((4 | g) ^ (rbn & 7)) << 4));
        }
#pragma unroll
        for (int kh = 0; kh < 2; ++kh)
#pragma unroll
            for (int i = 0; i < 4; ++i)
#pragma unroll
                for (int j = 0; j < 4; ++j)
                    acc[i][j] = __builtin_amdgcn_mfma_f32_16x16x32_bf16(af[kh][i], bfr[kh][j], acc[i][j], 0, 0, 0);
        __syncthreads();
    }

#pragma unroll
    for (int i = 0; i < 4; ++i)
#pragma unroll
        for (int j = 0; j < 4; ++j)
            store_tile(acc[i][j], m0 + wr * 64 + i * 16, n0 + wc * 64 + j * 16,
                       lane, bias, out, N, out_f32, bias_row);
}

// ---------------- MFMA causal flash attention, block-shared LDS K/V, paired chunks ----------------
// Block = TWO 128-row q-chunks {pi, 15-pi} of one (b,h) -> every block runs exactly 34 kv-tile
// iterations (load balance; fixes the chunk-major 15%-occupancy skew). 4 waves x 32 q rows.
// Scores computed in log2 domain (Q pre-scaled by 0.125*log2e, exp2f softmax — v_exp_f32 IS 2^x).
__global__ __launch_bounds__(256) void attn_mfma2(
    const __bf16* __restrict__ Q, const __bf16* __restrict__ Kg,
    const __bf16* __restrict__ Vt, __bf16* __restrict__ Ab)
{
    __shared__ __bf16 ldsK[64][64];    // [kv][d], 16B chunks XOR-swizzled by kv&7
    __shared__ __bf16 ldsV[64][64];    // [d][kv], 16B chunks XOR-swizzled by d&7
    __shared__ __bf16 ldsE[4][32 * 72];

    const int lane = threadIdx.x & 63, widx = threadIdx.x >> 6;
    const int c = lane & 15, g = lane >> 4;
    const int bid = blockIdx.x;
    const int bh = bid & 63, pi = bid >> 6;      // pi in 0..7 -> chunks {pi, 15-pi}
    const int b = bh >> 4, h = bh & 15;

    const int sr8 = lane >> 3;
    const int sc8 = lane & 7;
    const float qscale = 0.125f * 1.4426950408889634f;   // fold log2e: softmax base-invariant

    for (int seg = 0; seg < 2; ++seg) {
        const int chunk = seg ? (15 - pi) : pi;
        const int q0w = chunk * 128 + widx * 32;

        // Q fragments [qi][hf], pre-scaled
        bf16x8 qf[2][2];
#pragma unroll
        for (int qi = 0; qi < 2; ++qi)
#pragma unroll
            for (int hf = 0; hf < 2; ++hf) {
                const long qa = ((long)(b * S_ + q0w + qi * 16 + c)) * H_ + h * HS_ + hf * 32 + g * 8;
                bf16x8 t = *reinterpret_cast<const bf16x8*>(Q + qa);
#pragma unroll
                for (int j = 0; j < 8; ++j) t[j] = (__bf16)(qscale * (float)t[j]);
                qf[qi][hf] = t;
            }

        f32x4 ot[4][2] = {};
        float m[2] = {-1e30f, -1e30f}, l[2] = {0.f, 0.f};
        const int nt = 2 * (chunk + 1);

        for (int t = 0; t < nt; ++t) {
            const int kt = t * 64;
#pragma unroll
            for (int it = 0; it < 2; ++it) {
                const int row = widx * 16 + it * 8 + sr8;
                gload16(Kg + ((long)(b * S_ + kt + row)) * H_ + h * HS_ + ((sc8 ^ (row & 7)) << 3),
                        &ldsK[widx * 16 + it * 8][0]);
            }
#pragma unroll
            for (int it = 0; it < 2; ++it) {
                const int dr = widx * 16 + it * 8 + sr8;
                gload16(Vt + ((long)(h * HS_ + dr)) * SG_ + b * S_ + kt + ((sc8 ^ (dr & 7)) << 3),
                        &ldsV[widx * 16 + it * 8][0]);
            }
            __syncthreads();

            if (kt <= q0w + 31) {
                // ---- QK^T ----
                f32x4 st[4][2] = {};
#pragma unroll
                for (int t4 = 0; t4 < 4; ++t4) {
                    const int r = t4 * 16 + c;
                    const char* kp = (const char*)&ldsK[r][0];
                    bf16x8 kf0 = *(const bf16x8*)(kp + (((g)     ^ (c & 7)) << 4));
                    bf16x8 kf1 = *(const bf16x8*)(kp + (((4 | g) ^ (c & 7)) << 4));
#pragma unroll
                    for (int qi = 0; qi < 2; ++qi) {
                        st[t4][qi] = __builtin_amdgcn_mfma_f32_16x16x32_bf16(kf0, qf[qi][0], st[t4][qi], 0, 0, 0);
                        st[t4][qi] = __builtin_amdgcn_mfma_f32_16x16x32_bf16(kf1, qf[qi][1], st[t4][qi], 0, 0, 0);
                    }
                }
                // ---- causal mask ----
                if (kt + 63 > q0w) {
#pragma unroll
                    for (int t4 = 0; t4 < 4; ++t4)
#pragma unroll
                        for (int qi = 0; qi < 2; ++qi)
#pragma unroll
                            for (int r = 0; r < 4; ++r)
                                if (kt + t4 * 16 + g * 4 + r > q0w + qi * 16 + c)
                                    st[t4][qi][r] = -1e30f;
                }
                // ---- online softmax (base-2) + PV ----
                bf16x8 pf[2][2];
                float fr[2];
#pragma unroll
                for (int qi = 0; qi < 2; ++qi) {
                    float pm = -1e30f;
#pragma unroll
                    for (int t4 = 0; t4 < 4; ++t4)
#pragma unroll
                        for (int r = 0; r < 4; ++r) pm = fmaxf(pm, st[t4][qi][r]);
                    pm = fmaxf(pm, __shfl_xor(pm, 16));
                    pm = fmaxf(pm, __shfl_xor(pm, 32));
                    const float mn = fmaxf(m[qi], pm);
                    fr[qi] = exp2f(m[qi] - mn);
                    m[qi] = mn;
                    float p[16], rs = 0.f;
#pragma unroll
                    for (int t4 = 0; t4 < 4; ++t4)
#pragma unroll
                        for (int r = 0; r < 4; ++r) {
                            const float e = exp2f(st[t4][qi][r] - mn);
                            p[t4 * 4 + r] = e; rs += e;
                        }
                    rs += __shfl_xor(rs, 16);
                    rs += __shfl_xor(rs, 32);
                    l[qi] = l[qi] * fr[qi] + rs;
#pragma unroll
                    for (int j = 0; j < 8; ++j) {
                        pf[0][qi][j] = (__bf16)p[j];
                        pf[1][qi][j] = (__bf16)p[8 + j];
                    }
                }
#pragma unroll
                for (int blk = 0; blk < 4; ++blk) {
#pragma unroll
                    for (int qi = 0; qi < 2; ++qi) ot[blk][qi] *= fr[qi];
                    const char* vp = (const char*)&ldsV[blk * 16 + c][0];
                    const int sw = c & 7;
#pragma unroll
                    for (int hf = 0; hf < 2; ++hf) {
                        bf16x4 lo = *(const bf16x4*)(vp + ((((hf << 2) + (g >> 1))     ^ sw) << 4) + ((g & 1) << 3));
                        bf16x4 hi = *(const bf16x4*)(vp + ((((hf << 2) + 2 + (g >> 1)) ^ sw) << 4) + ((g & 1) << 3));
                        bf16x8 vf;
                        vf[0] = lo[0]; vf[1] = lo[1]; vf[2] = lo[2]; vf[3] = lo[3];
                        vf[4] = hi[0]; vf[5] = hi[1]; vf[6] = hi[2]; vf[7] = hi[3];
#pragma unroll
                        for (int qi = 0; qi < 2; ++qi)
                            ot[blk][qi] = __builtin_amdgcn_mfma_f32_16x16x32_bf16(vf, pf[hf][qi], ot[blk][qi], 0, 0, 0);
                    }
                }
            }
            __syncthreads();
        }

        // ---- epilogue (per-wave LDS region, no barrier needed) ----
        __bf16* myo = ldsE[widx];
#pragma unroll
        for (int qi = 0; qi < 2; ++qi) {
            const float invl = 1.0f / l[qi];
#pragma unroll
            for (int blk = 0; blk < 4; ++blk) {
                bf16x4 tv;
#pragma unroll
                for (int r = 0; r < 4; ++r) tv[r] = (__bf16)(ot[blk][qi][r] * invl);
                *reinterpret_cast<bf16x4*>(myo + (qi * 16 + c) * 72 + blk * 16 + g * 4) = tv;
            }
        }
#pragma unroll
        for (int half = 0; half < 2; ++half) {
            const int qr = lane >> 2, dc = (lane & 3) * 16;
            const __bf16* src = myo + (half * 16 + qr) * 72 + dc;
            bf16x8 r0 = *reinterpret_cast<const bf16x8*>(src);
            bf16x8 r1 = *reinterpret_cast<const bf16x8*>(src + 8);
            __bf16* dst = Ab + ((long)(b * S_ + q0w + half * 16 + qr)) * H_ + h * HS_ + dc;
            *reinterpret_cast<bf16x8*>(dst) = r0;
            *reinterpret_cast<bf16x8*>(dst + 8) = r1;
        }
    }
}

// ---------------- launch ----------------
extern "C" void kernel_launch(void* const* d_in, const int* in_sizes, int n_in,
                              void* d_out, int out_size, void* d_ws, size_t ws_size,
                              hipStream_t stream) {
    const float* x  = (const float*)d_in[0];
    const float* Wq = (const float*)d_in[1];
    const float* bq = (const float*)d_in[2];
    const float* Wk = (const float*)d_in[3];
    const float* bk = (const float*)d_in[4];
    const float* Wv = (const float*)d_in[5];
    const float* bv = (const float*)d_in[6];
    const float* Wp = (const float*)d_in[7];
    const float* bp = (const float*)d_in[8];
    float* out = (float*)d_out;

    const int M = SG_;         // 8192
    const int N = H_;          // 1024
    const int K = H_;          // 1024

    char* ws = (char*)d_ws;
    size_t off = 0;
    __bf16* xb  = (__bf16*)(ws + off); off += (size_t)M * K * 2;
    __bf16* Wqb = (__bf16*)(ws + off); off += (size_t)N * K * 2;
    __bf16* Wkb = (__bf16*)(ws + off); off += (size_t)N * K * 2;
    __bf16* Wvb = (__bf16*)(ws + off); off += (size_t)N * K * 2;
    __bf16* Wpb = (__bf16*)(ws + off); off += (size_t)N * K * 2;
    __bf16* Qb  = (__bf16*)(ws + off); off += (size_t)M * H_ * 2;
    __bf16* Kbf = (__bf16*)(ws + off); off += (size_t)M * H_ * 2;
    __bf16* Vt  = (__bf16*)(ws + off); off += (size_t)M * H_ * 2;   // V^T [1024][8192]
    __bf16* Ab  = (__bf16*)(ws + off); off += (size_t)M * H_ * 2;

    {
        int n4 = M * K / 4;
        cvt_f32_bf16<<<(n4 + 255) / 256, 256, 0, stream>>>(x, xb, n4);
        int w4 = N * K / 4;
        dim3 gw((w4 + 255) / 256, 4);
        cvt_w4<<<gw, 256, 0, stream>>>(Wq, Wk, Wv, Wp, Wqb, Wkb, Wvb, Wpb, w4);
    }

    dim3 gg(N / 128, M / 128);
    gemm128<<<gg, 256, 0, stream>>>(xb, Wqb, bq, Qb,  M, N, K, 0, 0);
    gemm128<<<gg, 256, 0, stream>>>(xb, Wkb, bk, Kbf, M, N, K, 0, 0);
    // V projection computed transposed: V^T[f][sg] = Wv[f] . x[sg] + bv[f]
    dim3 gv(M / 128, N / 128);
    gemm128<<<gv, 256, 0, stream>>>(Wvb, xb, bv, Vt, N, M, K, 0, 1);

    // attention: 512 blocks (8 chunk-pairs x 64 bh), every block = 34 kv-tile iterations
    attn_mfma2<<<512, 256, 0, stream>>>(Qb, Kbf, Vt, Ab);

    // output projection -> fp32 d_out
    gemm128<<<gg, 256, 0, stream>>>(Ab, Wpb, bp, out, M, N, K, 1, 0);
}

// Round 9
// 306.949 us; speedup vs baseline: 59.5717x; 1.0249x over previous
//
#include <hip/hip_runtime.h>

#define B_ 4
#define S_ 2048
#define H_ 1024
#define NH_ 16
#define HS_ 64
#define SG_ (B_*S_)   // 8192 total sequence rows

typedef __bf16 bf16x8 __attribute__((ext_vector_type(8)));
typedef __bf16 bf16x4 __attribute__((ext_vector_type(4)));
typedef float  f32x4  __attribute__((ext_vector_type(4)));

#define M3(a,b,c) fmaxf(fmaxf((a),(b)),(c))

// async global->LDS, 16B per lane. dest = wave-uniform base (lane*16 auto-appended).
__device__ __forceinline__ void gload16(const void* g, void* l) {
    __builtin_amdgcn_global_load_lds(
        (const __attribute__((address_space(1))) void*)g,
        (__attribute__((address_space(3))) void*)l,
        16, 0, 0);
}

// ---------------- fp32 -> bf16 conversion ----------------
__global__ void cvt_f32_bf16(const float* __restrict__ in, __bf16* __restrict__ out, int n4) {
    int i = blockIdx.x * blockDim.x + threadIdx.x;
    if (i >= n4) return;
    float4 v = reinterpret_cast<const float4*>(in)[i];
    bf16x4 o;
    o[0] = (__bf16)v.x; o[1] = (__bf16)v.y; o[2] = (__bf16)v.z; o[3] = (__bf16)v.w;
    reinterpret_cast<bf16x4*>(out)[i] = o;
}

// fused convert of the 4 weight matrices (one launch instead of four)
__global__ void cvt_w4(const float* __restrict__ w0, const float* __restrict__ w1,
                       const float* __restrict__ w2, const float* __restrict__ w3,
                       __bf16* __restrict__ o0, __bf16* __restrict__ o1,
                       __bf16* __restrict__ o2, __bf16* __restrict__ o3, int n4) {
    int i = blockIdx.x * blockDim.x + threadIdx.x;
    if (i >= n4) return;
    const float* in; __bf16* out;
    switch (blockIdx.y) {
        case 0: in = w0; out = o0; break;
        case 1: in = w1; out = o1; break;
        case 2: in = w2; out = o2; break;
        default: in = w3; out = o3; break;
    }
    float4 v = reinterpret_cast<const float4*>(in)[i];
    bf16x4 o;
    o[0] = (__bf16)v.x; o[1] = (__bf16)v.y; o[2] = (__bf16)v.z; o[3] = (__bf16)v.w;
    reinterpret_cast<bf16x4*>(out)[i] = o;
}

// ---------------- 128x128 MFMA GEMM, BK=64, 2-phase double-buffered LDS ----------------
// Y[m,n] = A[m,:].W[n,:] + bias. LDS [2][128][64] bf16 per operand (64KB), 16B chunks
// XOR-swizzled by row&7 both sides. Prefetch tile kt+1 while computing kt; single barrier
// per iter (its implicit vmcnt(0) waits loads that had the whole compute phase to land).
__device__ __forceinline__ void store_tile(const f32x4& acc, long mbase, long nbase, int lane,
                                           const float* __restrict__ bias, void* __restrict__ out,
                                           long N, int out_f32, int bias_row) {
    const int r16 = lane & 15, kg = lane >> 4;
    const long col = nbase + r16;
    const float bc = bias_row ? 0.f : bias[col];
#pragma unroll
    for (int r = 0; r < 4; ++r) {
        const long row = mbase + kg * 4 + r;
        const float v = acc[r] + (bias_row ? bias[row] : bc);
        if (out_f32) ((float*)out)[row * N + col] = v;
        else         ((__bf16*)out)[row * N + col] = (__bf16)v;
    }
}

__global__ __launch_bounds__(256) void gemm128(
    const __bf16* __restrict__ A, const __bf16* __restrict__ W,
    const float* __restrict__ bias, void* __restrict__ out,
    int M, int N, int K, int out_f32, int bias_row)
{
    __shared__ __bf16 sA[2][128][64];
    __shared__ __bf16 sB[2][128][64];
    const int lane = threadIdx.x & 63, widx = threadIdx.x >> 6;
    const int wr = widx >> 1, wc = widx & 1;
    const int c = lane & 15, g = lane >> 4;
    const long m0 = (long)blockIdx.y * 128, n0 = (long)blockIdx.x * 128;
    const int sr8 = lane >> 3;        // staging row within 8-row group
    const int sc8 = lane & 7;         // staging 16B chunk (8 per 128B row)

    auto STAGE = [&](int buf, int k0) {
#pragma unroll
        for (int it = 0; it < 4; ++it) {
            const int rb = it * 32 + widx * 8;
            const int row = rb + sr8;
            gload16(A + (m0 + row) * K + k0 + ((sc8 ^ (row & 7)) << 3), &sA[buf][rb][0]);
            gload16(W + (n0 + row) * K + k0 + ((sc8 ^ (row & 7)) << 3), &sB[buf][rb][0]);
        }
    };

    f32x4 acc[4][4] = {};

    STAGE(0, 0);
    __syncthreads();
    const int NK = K >> 6;
    for (int kt = 0; kt < NK; ++kt) {
        const int cur = kt & 1;
        if (kt + 1 < NK) STAGE(cur ^ 1, (kt + 1) << 6);

        bf16x8 af[2][4], bfr[2][4];
#pragma unroll
        for (int i = 0; i < 4; ++i) {
            const int ra = wr * 64 + i * 16 + c;
            const char* ap = (const char*)&sA[cur][ra][0];
            af[0][i] = *(const bf16x8*)(ap + ((( g    ) ^ (ra & 7)) << 4));
            af[1][i] = *(const bf16x8*)(ap + (((4 | g) ^ (ra & 7)) << 4));
            const int rbn = wc * 64 + i * 16 + c;
            const char* bp = (const char*)&sB[cur][rbn][0];
            bfr[0][i] = *(const bf16x8*)(bp + ((( g    ) ^ (rbn & 7)) << 4));
            bfr[1][i] = *(const bf16x8*)(bp + (((4 | g) ^ (rbn & 7)) << 4));
        }
#pragma unroll
        for (int kh = 0; kh < 2; ++kh)
#pragma unroll
            for (int i = 0; i < 4; ++i)
#pragma unroll
                for (int j = 0; j < 4; ++j)
                    acc[i][j] = __builtin_amdgcn_mfma_f32_16x16x32_bf16(af[kh][i], bfr[kh][j], acc[i][j], 0, 0, 0);
        __syncthreads();
    }

#pragma unroll
    for (int i = 0; i < 4; ++i)
#pragma unroll
        for (int j = 0; j < 4; ++j)
            store_tile(acc[i][j], m0 + wr * 64 + i * 16, n0 + wc * 64 + j * 16,
                       lane, bias, out, N, out_f32, bias_row);
}

// ---------------- MFMA causal flash attention ----------------
// Block = paired 128-row q-chunks {pi, 15-pi} (uniform 34 kv-iters). 4 waves x 32 q rows.
// 2-phase double-buffered K/V LDS staging; base-2 softmax with defer-max (skip O-rescale
// when __all(pm - m <= 8), wave-uniform); max3-friendly reduction trees.
__global__ __launch_bounds__(256) void attn_mfma2(
    const __bf16* __restrict__ Q, const __bf16* __restrict__ Kg,
    const __bf16* __restrict__ Vt, __bf16* __restrict__ Ab)
{
    __shared__ __bf16 ldsK[2][64][64];   // [buf][kv][d], 16B chunks XOR-swizzled by kv&7
    __shared__ __bf16 ldsV[2][64][64];   // [buf][d][kv], 16B chunks XOR-swizzled by d&7
    __shared__ __bf16 ldsE[4][32 * 72];

    const int lane = threadIdx.x & 63, widx = threadIdx.x >> 6;
    const int c = lane & 15, g = lane >> 4;
    const int bid = blockIdx.x;
    const int bh = bid & 63, pi = bid >> 6;      // pi in 0..7 -> chunks {pi, 15-pi}
    const int b = bh >> 4, h = bh & 15;

    const int sr8 = lane >> 3;
    const int sc8 = lane & 7;
    const float qscale = 0.125f * 1.4426950408889634f;   // fold log2e (base-2 softmax)

    auto STAGEKV = [&](int buf, int kt) {
#pragma unroll
        for (int it = 0; it < 2; ++it) {
            const int row = widx * 16 + it * 8 + sr8;
            gload16(Kg + ((long)(b * S_ + kt + row)) * H_ + h * HS_ + ((sc8 ^ (row & 7)) << 3),
                    &ldsK[buf][widx * 16 + it * 8][0]);
        }
#pragma unroll
        for (int it = 0; it < 2; ++it) {
            const int dr = widx * 16 + it * 8 + sr8;
            gload16(Vt + ((long)(h * HS_ + dr)) * SG_ + b * S_ + kt + ((sc8 ^ (dr & 7)) << 3),
                    &ldsV[buf][widx * 16 + it * 8][0]);
        }
    };

    for (int seg = 0; seg < 2; ++seg) {
        const int chunk = seg ? (15 - pi) : pi;
        const int q0w = chunk * 128 + widx * 32;

        // Q fragments [qi][hf], pre-scaled
        bf16x8 qf[2][2];
#pragma unroll
        for (int qi = 0; qi < 2; ++qi)
#pragma unroll
            for (int hf = 0; hf < 2; ++hf) {
                const long qa = ((long)(b * S_ + q0w + qi * 16 + c)) * H_ + h * HS_ + hf * 32 + g * 8;
                bf16x8 t = *reinterpret_cast<const bf16x8*>(Q + qa);
#pragma unroll
                for (int j = 0; j < 8; ++j) t[j] = (__bf16)(qscale * (float)t[j]);
                qf[qi][hf] = t;
            }

        f32x4 ot[4][2] = {};
        float m[2] = {-1e30f, -1e30f}, l[2] = {0.f, 0.f};
        const int nt = 2 * (chunk + 1);

        STAGEKV(0, 0);
        __syncthreads();

        for (int t = 0; t < nt; ++t) {
            const int cur = t & 1;
            if (t + 1 < nt) STAGEKV(cur ^ 1, (t + 1) * 64);
            const int kt = t * 64;

            if (kt <= q0w + 31) {
                // ---- QK^T ----
                f32x4 st[4][2] = {};
#pragma unroll
                for (int t4 = 0; t4 < 4; ++t4) {
                    const int r = t4 * 16 + c;
                    const char* kp = (const char*)&ldsK[cur][r][0];
                    bf16x8 kf0 = *(const bf16x8*)(kp + (((g)     ^ (c & 7)) << 4));
                    bf16x8 kf1 = *(const bf16x8*)(kp + (((4 | g) ^ (c & 7)) << 4));
#pragma unroll
                    for (int qi = 0; qi < 2; ++qi) {
                        st[t4][qi] = __builtin_amdgcn_mfma_f32_16x16x32_bf16(kf0, qf[qi][0], st[t4][qi], 0, 0, 0);
                        st[t4][qi] = __builtin_amdgcn_mfma_f32_16x16x32_bf16(kf1, qf[qi][1], st[t4][qi], 0, 0, 0);
                    }
                }
                // ---- causal mask (diagonal tiles only) ----
                if (kt + 63 > q0w) {
#pragma unroll
                    for (int t4 = 0; t4 < 4; ++t4)
#pragma unroll
                        for (int qi = 0; qi < 2; ++qi)
#pragma unroll
                            for (int r = 0; r < 4; ++r)
                                if (kt + t4 * 16 + g * 4 + r > q0w + qi * 16 + c)
                                    st[t4][qi][r] = -1e30f;
                }
                // ---- online softmax (base-2, defer-max) ----
                bf16x8 pf[2][2];
                float fr[2];
                int resc = 0;
#pragma unroll
                for (int qi = 0; qi < 2; ++qi) {
                    const float a0 = M3(st[0][qi][0], st[0][qi][1], st[0][qi][2]);
                    const float a1 = M3(st[0][qi][3], st[1][qi][0], st[1][qi][1]);
                    const float a2 = M3(st[1][qi][2], st[1][qi][3], st[2][qi][0]);
                    const float a3 = M3(st[2][qi][1], st[2][qi][2], st[2][qi][3]);
                    const float a4 = M3(st[3][qi][0], st[3][qi][1], st[3][qi][2]);
                    float pm = M3(M3(a0, a1, a2), a3, fmaxf(a4, st[3][qi][3]));
                    pm = fmaxf(pm, __shfl_xor(pm, 16));
                    pm = fmaxf(pm, __shfl_xor(pm, 32));
                    const int defer = __all(pm - m[qi] <= 8.0f);
                    float mn;
                    if (defer) {
                        mn = m[qi]; fr[qi] = 1.0f;
                    } else {
                        mn = fmaxf(m[qi], pm);
                        fr[qi] = exp2f(m[qi] - mn);
                        m[qi] = mn;
                        resc = 1;
                    }
                    float p[16], rs = 0.f;
#pragma unroll
                    for (int t4 = 0; t4 < 4; ++t4)
#pragma unroll
                        for (int r = 0; r < 4; ++r) {
                            const float e = exp2f(st[t4][qi][r] - mn);
                            p[t4 * 4 + r] = e; rs += e;
                        }
                    rs += __shfl_xor(rs, 16);
                    rs += __shfl_xor(rs, 32);
                    l[qi] = l[qi] * fr[qi] + rs;
#pragma unroll
                    for (int j = 0; j < 8; ++j) {
                        pf[0][qi][j] = (__bf16)p[j];
                        pf[1][qi][j] = (__bf16)p[8 + j];
                    }
                }
                // ---- PV (rescale only when some wave-row max grew) ----
                if (resc) {
#pragma unroll
                    for (int blk = 0; blk < 4; ++blk) {
                        ot[blk][0] *= fr[0];
                        ot[blk][1] *= fr[1];
                    }
                }
#pragma unroll
                for (int blk = 0; blk < 4; ++blk) {
                    const char* vp = (const char*)&ldsV[cur][blk * 16 + c][0];
                    const int sw = c & 7;
#pragma unroll
                    for (int hf = 0; hf < 2; ++hf) {
                        bf16x4 lo = *(const bf16x4*)(vp + ((((hf << 2) + (g >> 1))     ^ sw) << 4) + ((g & 1) << 3));
                        bf16x4 hi = *(const bf16x4*)(vp + ((((hf << 2) + 2 + (g >> 1)) ^ sw) << 4) + ((g & 1) << 3));
                        bf16x8 vf;
                        vf[0] = lo[0]; vf[1] = lo[1]; vf[2] = lo[2]; vf[3] = lo[3];
                        vf[4] = hi[0]; vf[5] = hi[1]; vf[6] = hi[2]; vf[7] = hi[3];
#pragma unroll
                        for (int qi = 0; qi < 2; ++qi)
                            ot[blk][qi] = __builtin_amdgcn_mfma_f32_16x16x32_bf16(vf, pf[hf][qi], ot[blk][qi], 0, 0, 0);
                    }
                }
            }
            __syncthreads();
        }

        // ---- epilogue (per-wave LDS region, no barrier needed) ----
        __bf16* myo = ldsE[widx];
#pragma unroll
        for (int qi = 0; qi < 2; ++qi) {
            const float invl = 1.0f / l[qi];
#pragma unroll
            for (int blk = 0; blk < 4; ++blk) {
                bf16x4 tv;
#pragma unroll
                for (int r = 0; r < 4; ++r) tv[r] = (__bf16)(ot[blk][qi][r] * invl);
                *reinterpret_cast<bf16x4*>(myo + (qi * 16 + c) * 72 + blk * 16 + g * 4) = tv;
            }
        }
#pragma unroll
        for (int half = 0; half < 2; ++half) {
            const int qr = lane >> 2, dc = (lane & 3) * 16;
            const __bf16* src = myo + (half * 16 + qr) * 72 + dc;
            bf16x8 r0 = *reinterpret_cast<const bf16x8*>(src);
            bf16x8 r1 = *reinterpret_cast<const bf16x8*>(src + 8);
            __bf16* dst = Ab + ((long)(b * S_ + q0w + half * 16 + qr)) * H_ + h * HS_ + dc;
            *reinterpret_cast<bf16x8*>(dst) = r0;
            *reinterpret_cast<bf16x8*>(dst + 8) = r1;
        }
    }
}

// ---------------- launch ----------------
extern "C" void kernel_launch(void* const* d_in, const int* in_sizes, int n_in,
                              void* d_out, int out_size, void* d_ws, size_t ws_size,
                              hipStream_t stream) {
    const float* x  = (const float*)d_in[0];
    const float* Wq = (const float*)d_in[1];
    const float* bq = (const float*)d_in[2];
    const float* Wk = (const float*)d_in[3];
    const float* bk = (const float*)d_in[4];
    const float* Wv = (const float*)d_in[5];
    const float* bv = (const float*)d_in[6];
    const float* Wp = (const float*)d_in[7];
    const float* bp = (const float*)d_in[8];
    float* out = (float*)d_out;

    const int M = SG_;         // 8192
    const int N = H_;          // 1024
    const int K = H_;          // 1024

    char* ws = (char*)d_ws;
    size_t off = 0;
    __bf16* xb  = (__bf16*)(ws + off); off += (size_t)M * K * 2;
    __bf16* Wqb = (__bf16*)(ws + off); off += (size_t)N * K * 2;
    __bf16* Wkb = (__bf16*)(ws + off); off += (size_t)N * K * 2;
    __bf16* Wvb = (__bf16*)(ws + off); off += (size_t)N * K * 2;
    __bf16* Wpb = (__bf16*)(ws + off); off += (size_t)N * K * 2;
    __bf16* Qb  = (__bf16*)(ws + off); off += (size_t)M * H_ * 2;
    __bf16* Kbf = (__bf16*)(ws + off); off += (size_t)M * H_ * 2;
    __bf16* Vt  = (__bf16*)(ws + off); off += (size_t)M * H_ * 2;   // V^T [1024][8192]
    __bf16* Ab  = (__bf16*)(ws + off); off += (size_t)M * H_ * 2;

    {
        int n4 = M * K / 4;
        cvt_f32_bf16<<<(n4 + 255) / 256, 256, 0, stream>>>(x, xb, n4);
        int w4 = N * K / 4;
        dim3 gw((w4 + 255) / 256, 4);
        cvt_w4<<<gw, 256, 0, stream>>>(Wq, Wk, Wv, Wp, Wqb, Wkb, Wvb, Wpb, w4);
    }

    dim3 gg(N / 128, M / 128);
    gemm128<<<gg, 256, 0, stream>>>(xb, Wqb, bq, Qb,  M, N, K, 0, 0);
    gemm128<<<gg, 256, 0, stream>>>(xb, Wkb, bk, Kbf, M, N, K, 0, 0);
    // V projection computed transposed: V^T[f][sg] = Wv[f] . x[sg] + bv[f]
    dim3 gv(M / 128, N / 128);
    gemm128<<<gv, 256, 0, stream>>>(Wvb, xb, bv, Vt, N, M, K, 0, 1);

    // attention: 512 blocks (8 chunk-pairs x 64 bh), every block = 34 kv-tile iterations
    attn_mfma2<<<512, 256, 0, stream>>>(Qb, Kbf, Vt, Ab);

    // output projection -> fp32 d_out
    gemm128<<<gg, 256, 0, stream>>>(Ab, Wpb, bp, out, M, N, K, 1, 0);
}

// Round 10
// 290.252 us; speedup vs baseline: 62.9986x; 1.0575x over previous
//
#include <hip/hip_runtime.h>

#define B_ 4
#define S_ 2048
#define H_ 1024
#define NH_ 16
#define HS_ 64
#define SG_ (B_*S_)   // 8192 total sequence rows

typedef __bf16 bf16x8 __attribute__((ext_vector_type(8)));
typedef __bf16 bf16x4 __attribute__((ext_vector_type(4)));
typedef float  f32x4  __attribute__((ext_vector_type(4)));

#define M3(a,b,c) fmaxf(fmaxf((a),(b)),(c))

// async global->LDS, 16B per lane. dest = wave-uniform base (lane*16 auto-appended).
__device__ __forceinline__ void gload16(const void* g, void* l) {
    __builtin_amdgcn_global_load_lds(
        (const __attribute__((address_space(1))) void*)g,
        (__attribute__((address_space(3))) void*)l,
        16, 0, 0);
}

// ---------------- fp32 -> bf16 conversion ----------------
__global__ void cvt_f32_bf16(const float* __restrict__ in, __bf16* __restrict__ out, int n4) {
    int i = blockIdx.x * blockDim.x + threadIdx.x;
    if (i >= n4) return;
    float4 v = reinterpret_cast<const float4*>(in)[i];
    bf16x4 o;
    o[0] = (__bf16)v.x; o[1] = (__bf16)v.y; o[2] = (__bf16)v.z; o[3] = (__bf16)v.w;
    reinterpret_cast<bf16x4*>(out)[i] = o;
}

// fused convert of the 4 weight matrices (one launch instead of four)
__global__ void cvt_w4(const float* __restrict__ w0, const float* __restrict__ w1,
                       const float* __restrict__ w2, const float* __restrict__ w3,
                       __bf16* __restrict__ o0, __bf16* __restrict__ o1,
                       __bf16* __restrict__ o2, __bf16* __restrict__ o3, int n4) {
    int i = blockIdx.x * blockDim.x + threadIdx.x;
    if (i >= n4) return;
    const float* in; __bf16* out;
    switch (blockIdx.y) {
        case 0: in = w0; out = o0; break;
        case 1: in = w1; out = o1; break;
        case 2: in = w2; out = o2; break;
        default: in = w3; out = o3; break;
    }
    float4 v = reinterpret_cast<const float4*>(in)[i];
    bf16x4 o;
    o[0] = (__bf16)v.x; o[1] = (__bf16)v.y; o[2] = (__bf16)v.z; o[3] = (__bf16)v.w;
    reinterpret_cast<bf16x4*>(out)[i] = o;
}

// ---------------- 128x128 MFMA GEMM, BK=32 single-buffer (m97 recipe, round-2-verified) ----
// mode 0: single fp32 out (out-proj), bias bp. mode 1: fused QKV, N=3072, writes
// Qb/Kbf/Vrow (bf16) with per-matrix bias; selection is block-uniform (tiles never
// straddle a 1024 boundary since 1024 % 128 == 0).
__global__ __launch_bounds__(256) void gemm128(
    const __bf16* __restrict__ A, const __bf16* __restrict__ W,
    const float* __restrict__ b0, const float* __restrict__ b1, const float* __restrict__ b2,
    void* __restrict__ o0, void* __restrict__ o1, void* __restrict__ o2,
    int K, int mode)
{
    __shared__ __bf16 sA[128][32];
    __shared__ __bf16 sB[128][32];
    const int lane = threadIdx.x & 63, widx = threadIdx.x >> 6;
    const int wr = widx >> 1, wc = widx & 1;
    const int c = lane & 15, g = lane >> 4;
    const long m0 = (long)blockIdx.y * 128, n0 = (long)blockIdx.x * 128;
    const int srow = lane >> 2;       // staging row within 16-row group
    const int schunk = lane & 3;      // 16B chunk within 64B row

    f32x4 acc[4][4] = {};

    for (int k0 = 0; k0 < K; k0 += 32) {
#pragma unroll
        for (int it = 0; it < 2; ++it) {
            const int row = widx * 32 + it * 16 + srow;
            gload16(A + (m0 + row) * K + k0 + ((schunk ^ (row & 3)) << 3),
                    &sA[widx * 32 + it * 16][0]);
            gload16(W + (n0 + row) * K + k0 + ((schunk ^ (row & 3)) << 3),
                    &sB[widx * 32 + it * 16][0]);
        }
        __syncthreads();
        bf16x8 af[4], bfr[4];
#pragma unroll
        for (int i = 0; i < 4; ++i) {
            const int ra = wr * 64 + i * 16 + c;
            af[i]  = *(const bf16x8*)((const char*)&sA[ra][0] + ((g ^ (ra & 3)) << 4));
            const int rb = wc * 64 + i * 16 + c;
            bfr[i] = *(const bf16x8*)((const char*)&sB[rb][0] + ((g ^ (rb & 3)) << 4));
        }
#pragma unroll
        for (int i = 0; i < 4; ++i)
#pragma unroll
            for (int j = 0; j < 4; ++j)
                acc[i][j] = __builtin_amdgcn_mfma_f32_16x16x32_bf16(af[i], bfr[j], acc[i][j], 0, 0, 0);
        __syncthreads();
    }

    // epilogue
    const float* bias; void* ob; int obf16;
    long ncl;
    if (mode == 1) {
        const int sel = (int)(n0 >> 10);
        bias = sel == 0 ? b0 : (sel == 1 ? b1 : b2);
        ob   = sel == 0 ? o0 : (sel == 1 ? o1 : o2);
        ncl  = n0 & 1023; obf16 = 1;
    } else {
        bias = b0; ob = o0; ncl = n0; obf16 = 0;
    }
#pragma unroll
    for (int i = 0; i < 4; ++i)
#pragma unroll
        for (int j = 0; j < 4; ++j) {
            const long col = ncl + wc * 64 + j * 16 + c;
            const float bv = bias[col];
#pragma unroll
            for (int r = 0; r < 4; ++r) {
                const long row = m0 + wr * 64 + i * 16 + g * 4 + r;
                const float v = acc[i][j][r] + bv;
                if (obf16) ((__bf16*)ob)[row * 1024 + col] = (__bf16)v;
                else       ((float*)ob)[row * 1024 + col] = v;
            }
        }
}

// ---------------- V transpose with baked fragment permutation ----------------
// Vt[h*64+d][sgg + o] = Vrow[sgg+kv][h*64+d],  o = hf*32 + g4*8 + hi*4 + r
// for kv = hf*32 + hi*16 + g4*4 + r. Makes the attention PV A-fragment a single
// contiguous bf16x8 read. One wave per 64x64 tile; 4 waves/block.
__global__ __launch_bounds__(256) void vtrans(const __bf16* __restrict__ Vrow,
                                              __bf16* __restrict__ Vt) {
    __shared__ __bf16 tl[4][64][80];   // pad 80: 160B row stride keeps b128 aligned
    const int lane = threadIdx.x & 63, w = threadIdx.x >> 6;
    const int tile = blockIdx.x * 4 + w;           // 0..2047
    const int h = tile & 15;
    const int sgg = (tile >> 4) << 6;
    const int r8 = lane >> 3, c8 = lane & 7;
#pragma unroll
    for (int it = 0; it < 8; ++it) {
        const int kv = it * 8 + r8;
        bf16x8 v = *(const bf16x8*)(Vrow + (long)(sgg + kv) * H_ + h * 64 + c8 * 8);
        *(bf16x8*)(&tl[w][kv][c8 * 8]) = v;
    }
    __syncthreads();
    const int d = lane;
#pragma unroll
    for (int hf = 0; hf < 2; ++hf)
#pragma unroll
        for (int hi = 0; hi < 2; ++hi)
#pragma unroll
            for (int g4 = 0; g4 < 4; ++g4) {
                const int kv = hf * 32 + hi * 16 + g4 * 4;
                const int o  = hf * 32 + g4 * 8 + hi * 4;
                bf16x4 t;
#pragma unroll
                for (int r = 0; r < 4; ++r) t[r] = tl[w][kv + r][d];
                *(bf16x4*)(Vt + (long)(h * 64 + d) * SG_ + sgg + o) = t;
            }
}

// ---------------- MFMA causal flash attention, 8 waves, shared staging ----------------
// Block = (pi, bh): waves 0-3 compute chunk pi, waves 4-7 chunk 15-pi, SHARING one
// double-buffered K/V staging (uniform NT = 32-2*pi iters). 16 waves/CU. PV A-fragment
// is a single swizzled ds_read_b128 thanks to vtrans' permuted Vt. Base-2 softmax with
// defer-max. Epilogue LDS aliases the staging buffers (safe after the final barrier).
__global__ __launch_bounds__(512) void attn_mfma3(
    const __bf16* __restrict__ Q, const __bf16* __restrict__ Kg,
    const __bf16* __restrict__ Vt, __bf16* __restrict__ Ab)
{
    __shared__ char smem[38400];                      // staging 32KB | epilogue 36.9KB
    __bf16 (*ldsK)[64][64] = (__bf16 (*)[64][64])smem;            // [2][64][64]
    __bf16 (*ldsV)[64][64] = (__bf16 (*)[64][64])(smem + 16384);  // [2][64][64]

    const int lane = threadIdx.x & 63, widx = threadIdx.x >> 6;   // widx 0..7
    const int c = lane & 15, g = lane >> 4;
    const int bid = blockIdx.x;
    const int bh = bid & 63, pi = bid >> 6;           // pi in 0..7
    const int b = bh >> 4, h = bh & 15;
    const int chunk = (widx < 4) ? pi : (15 - pi);
    const int q0w = chunk * 128 + (widx & 3) * 32;

    const int sr8 = lane >> 3;
    const int sc8 = lane & 7;
    const float qscale = 0.125f * 1.4426950408889634f;

    // Q fragments [qi][hf], pre-scaled
    bf16x8 qf[2][2];
#pragma unroll
    for (int qi = 0; qi < 2; ++qi)
#pragma unroll
        for (int hf = 0; hf < 2; ++hf) {
            const long qa = ((long)(b * S_ + q0w + qi * 16 + c)) * H_ + h * HS_ + hf * 32 + g * 8;
            bf16x8 t = *reinterpret_cast<const bf16x8*>(Q + qa);
#pragma unroll
            for (int j = 0; j < 8; ++j) t[j] = (__bf16)(qscale * (float)t[j]);
            qf[qi][hf] = t;
        }

    f32x4 ot[4][2] = {};
    float m[2] = {-1e30f, -1e30f}, l[2] = {0.f, 0.f};
    const int NT = 32 - 2 * pi;       // covers long chunk exactly; short chunk guarded

    // each wave stages 8 rows of K and 8 rows of V^T per tile
    auto STAGEKV = [&](int buf, int kt) {
        const int row = widx * 8 + sr8;
        gload16(Kg + ((long)(b * S_ + kt + row)) * H_ + h * HS_ + ((sc8 ^ (row & 7)) << 3),
                &ldsK[buf][widx * 8][0]);
        gload16(Vt + ((long)(h * HS_ + row)) * SG_ + b * S_ + kt + ((sc8 ^ (row & 7)) << 3),
                &ldsV[buf][widx * 8][0]);
    };

    STAGEKV(0, 0);
    __syncthreads();

    for (int t = 0; t < NT; ++t) {
        const int cur = t & 1;
        if (t + 1 < NT) STAGEKV(cur ^ 1, (t + 1) * 64);
        const int kt = t * 64;

        if (kt <= q0w + 31) {
            // ---- QK^T ----
            f32x4 st[4][2] = {};
#pragma unroll
            for (int t4 = 0; t4 < 4; ++t4) {
                const int r = t4 * 16 + c;
                const char* kp = (const char*)&ldsK[cur][r][0];
                bf16x8 kf0 = *(const bf16x8*)(kp + (((g)     ^ (c & 7)) << 4));
                bf16x8 kf1 = *(const bf16x8*)(kp + (((4 | g) ^ (c & 7)) << 4));
#pragma unroll
                for (int qi = 0; qi < 2; ++qi) {
                    st[t4][qi] = __builtin_amdgcn_mfma_f32_16x16x32_bf16(kf0, qf[qi][0], st[t4][qi], 0, 0, 0);
                    st[t4][qi] = __builtin_amdgcn_mfma_f32_16x16x32_bf16(kf1, qf[qi][1], st[t4][qi], 0, 0, 0);
                }
            }
            // ---- causal mask (diagonal tiles only) ----
            if (kt + 63 > q0w) {
#pragma unroll
                for (int t4 = 0; t4 < 4; ++t4)
#pragma unroll
                    for (int qi = 0; qi < 2; ++qi)
#pragma unroll
                        for (int r = 0; r < 4; ++r)
                            if (kt + t4 * 16 + g * 4 + r > q0w + qi * 16 + c)
                                st[t4][qi][r] = -1e30f;
            }
            // ---- online softmax (base-2, defer-max) ----
            bf16x8 pf[2][2];
            float fr[2];
            int resc = 0;
#pragma unroll
            for (int qi = 0; qi < 2; ++qi) {
                const float a0 = M3(st[0][qi][0], st[0][qi][1], st[0][qi][2]);
                const float a1 = M3(st[0][qi][3], st[1][qi][0], st[1][qi][1]);
                const float a2 = M3(st[1][qi][2], st[1][qi][3], st[2][qi][0]);
                const float a3 = M3(st[2][qi][1], st[2][qi][2], st[2][qi][3]);
                const float a4 = M3(st[3][qi][0], st[3][qi][1], st[3][qi][2]);
                float pm = M3(M3(a0, a1, a2), a3, fmaxf(a4, st[3][qi][3]));
                pm = fmaxf(pm, __shfl_xor(pm, 16));
                pm = fmaxf(pm, __shfl_xor(pm, 32));
                const int defer = __all(pm - m[qi] <= 8.0f);
                float mn;
                if (defer) {
                    mn = m[qi]; fr[qi] = 1.0f;
                } else {
                    mn = fmaxf(m[qi], pm);
                    fr[qi] = exp2f(m[qi] - mn);
                    m[qi] = mn;
                    resc = 1;
                }
                float p[16], rs = 0.f;
#pragma unroll
                for (int t4 = 0; t4 < 4; ++t4)
#pragma unroll
                    for (int r = 0; r < 4; ++r) {
                        const float e = exp2f(st[t4][qi][r] - mn);
                        p[t4 * 4 + r] = e; rs += e;
                    }
                rs += __shfl_xor(rs, 16);
                rs += __shfl_xor(rs, 32);
                l[qi] = l[qi] * fr[qi] + rs;
#pragma unroll
                for (int j = 0; j < 8; ++j) {
                    pf[0][qi][j] = (__bf16)p[j];
                    pf[1][qi][j] = (__bf16)p[8 + j];
                }
            }
            // ---- PV ----
            if (resc) {
#pragma unroll
                for (int blk = 0; blk < 4; ++blk) {
                    ot[blk][0] *= fr[0];
                    ot[blk][1] *= fr[1];
                }
            }
#pragma unroll
            for (int blk = 0; blk < 4; ++blk) {
                const char* vp = (const char*)&ldsV[cur][blk * 16 + c][0];
#pragma unroll
                for (int hf = 0; hf < 2; ++hf) {
                    bf16x8 vf = *(const bf16x8*)(vp + (((hf * 4 + g) ^ (c & 7)) << 4));
#pragma unroll
                    for (int qi = 0; qi < 2; ++qi)
                        ot[blk][qi] = __builtin_amdgcn_mfma_f32_16x16x32_bf16(vf, pf[hf][qi], ot[blk][qi], 0, 0, 0);
                }
            }
        }
        __syncthreads();
    }

    // ---- epilogue: per-wave region aliased over the (now-dead) staging LDS ----
    __bf16* myo = (__bf16*)smem + widx * (32 * 72);
#pragma unroll
    for (int qi = 0; qi < 2; ++qi) {
        const float invl = 1.0f / l[qi];
#pragma unroll
        for (int blk = 0; blk < 4; ++blk) {
            bf16x4 tv;
#pragma unroll
            for (int r = 0; r < 4; ++r) tv[r] = (__bf16)(ot[blk][qi][r] * invl);
            *reinterpret_cast<bf16x4*>(myo + (qi * 16 + c) * 72 + blk * 16 + g * 4) = tv;
        }
    }
#pragma unroll
    for (int half = 0; half < 2; ++half) {
        const int qr = lane >> 2, dc = (lane & 3) * 16;
        const __bf16* src = myo + (half * 16 + qr) * 72 + dc;
        bf16x8 r0 = *reinterpret_cast<const bf16x8*>(src);
        bf16x8 r1 = *reinterpret_cast<const bf16x8*>(src + 8);
        __bf16* dst = Ab + ((long)(b * S_ + q0w + half * 16 + qr)) * H_ + h * HS_ + dc;
        *reinterpret_cast<bf16x8*>(dst) = r0;
        *reinterpret_cast<bf16x8*>(dst + 8) = r1;
    }
}

// ---------------- launch ----------------
extern "C" void kernel_launch(void* const* d_in, const int* in_sizes, int n_in,
                              void* d_out, int out_size, void* d_ws, size_t ws_size,
                              hipStream_t stream) {
    const float* x  = (const float*)d_in[0];
    const float* Wq = (const float*)d_in[1];
    const float* bq = (const float*)d_in[2];
    const float* Wk = (const float*)d_in[3];
    const float* bk = (const float*)d_in[4];
    const float* Wv = (const float*)d_in[5];
    const float* bv = (const float*)d_in[6];
    const float* Wp = (const float*)d_in[7];
    const float* bp = (const float*)d_in[8];
    float* out = (float*)d_out;

    const int M = SG_;         // 8192
    const int K = H_;          // 1024

    char* ws = (char*)d_ws;
    size_t off = 0;
    __bf16* xb   = (__bf16*)(ws + off); off += (size_t)M * K * 2;     // 16MB; dead after QKV gemm
    __bf16* Wqb  = (__bf16*)(ws + off); off += (size_t)H_ * K * 2;    // Wq,Wk,Wv contiguous (fused N=3072)
    __bf16* Wkb  = (__bf16*)(ws + off); off += (size_t)H_ * K * 2;
    __bf16* Wvb  = (__bf16*)(ws + off); off += (size_t)H_ * K * 2;
    __bf16* Wpb  = (__bf16*)(ws + off); off += (size_t)H_ * K * 2;
    __bf16* Qb   = (__bf16*)(ws + off); off += (size_t)M * H_ * 2;
    __bf16* Kbf  = (__bf16*)(ws + off); off += (size_t)M * H_ * 2;
    __bf16* Vrow = (__bf16*)(ws + off); off += (size_t)M * H_ * 2;    // row-major V (+bias)
    __bf16* Ab   = (__bf16*)(ws + off); off += (size_t)M * H_ * 2;
    __bf16* Vt   = xb;                                                 // alias: permuted V^T [1024][8192]

    {
        int n4 = M * K / 4;
        cvt_f32_bf16<<<(n4 + 255) / 256, 256, 0, stream>>>(x, xb, n4);
        int w4 = H_ * K / 4;
        dim3 gw((w4 + 255) / 256, 4);
        cvt_w4<<<gw, 256, 0, stream>>>(Wq, Wk, Wv, Wp, Wqb, Wkb, Wvb, Wpb, w4);
    }

    // fused QKV projection: [8192 x 3072] = xb @ [Wq;Wk;Wv]^T, 1536 blocks (6/CU)
    {
        dim3 g(3 * H_ / 128, M / 128);
        gemm128<<<g, 256, 0, stream>>>(xb, Wqb, bq, bk, bv, Qb, Kbf, Vrow, K, 1);
    }

    // V transpose with fragment permutation (reads Vrow, writes Vt==xb after QKV gemm done)
    vtrans<<<512, 256, 0, stream>>>(Vrow, Vt);

    // attention: 512 blocks x 8 waves (paired chunks share staging)
    attn_mfma3<<<512, 512, 0, stream>>>(Qb, Kbf, Vt, Ab);

    // output projection -> fp32 d_out
    {
        dim3 g(H_ / 128, M / 128);
        gemm128<<<g, 256, 0, stream>>>(Ab, Wpb, bp, nullptr, nullptr, out, nullptr, nullptr, K, 0);
    }
}

// Round 11
// 269.442 us; speedup vs baseline: 67.8642x; 1.0772x over previous
//
#include <hip/hip_runtime.h>

#define B_ 4
#define S_ 2048
#define H_ 1024
#define NH_ 16
#define HS_ 64
#define SG_ (B_*S_)   // 8192 total sequence rows

typedef __bf16 bf16x8 __attribute__((ext_vector_type(8)));
typedef __bf16 bf16x4 __attribute__((ext_vector_type(4)));
typedef float  f32x4  __attribute__((ext_vector_type(4)));

#define M3(a,b,c) fmaxf(fmaxf((a),(b)),(c))

// raw HW transcendental: v_exp_f32 computes 2^x (ISA). exp2f() goes through ocml's
// checked sequence; this is the single-instruction form.
__device__ __forceinline__ float fexp2(float x) {
    float r; asm("v_exp_f32 %0, %1" : "=v"(r) : "v"(x)); return r;
}

// async global->LDS, 16B per lane. dest = wave-uniform base (lane*16 auto-appended).
__device__ __forceinline__ void gload16(const void* g, void* l) {
    __builtin_amdgcn_global_load_lds(
        (const __attribute__((address_space(1))) void*)g,
        (__attribute__((address_space(3))) void*)l,
        16, 0, 0);
}

// ---------------- fp32 -> bf16 conversion ----------------
__global__ void cvt_f32_bf16(const float* __restrict__ in, __bf16* __restrict__ out, int n4) {
    int i = blockIdx.x * blockDim.x + threadIdx.x;
    if (i >= n4) return;
    float4 v = reinterpret_cast<const float4*>(in)[i];
    bf16x4 o;
    o[0] = (__bf16)v.x; o[1] = (__bf16)v.y; o[2] = (__bf16)v.z; o[3] = (__bf16)v.w;
    reinterpret_cast<bf16x4*>(out)[i] = o;
}

// fused convert of the 4 weight matrices (one launch instead of four)
__global__ void cvt_w4(const float* __restrict__ w0, const float* __restrict__ w1,
                       const float* __restrict__ w2, const float* __restrict__ w3,
                       __bf16* __restrict__ o0, __bf16* __restrict__ o1,
                       __bf16* __restrict__ o2, __bf16* __restrict__ o3, int n4) {
    int i = blockIdx.x * blockDim.x + threadIdx.x;
    if (i >= n4) return;
    const float* in; __bf16* out;
    switch (blockIdx.y) {
        case 0: in = w0; out = o0; break;
        case 1: in = w1; out = o1; break;
        case 2: in = w2; out = o2; break;
        default: in = w3; out = o3; break;
    }
    float4 v = reinterpret_cast<const float4*>(in)[i];
    bf16x4 o;
    o[0] = (__bf16)v.x; o[1] = (__bf16)v.y; o[2] = (__bf16)v.z; o[3] = (__bf16)v.w;
    reinterpret_cast<bf16x4*>(out)[i] = o;
}

// ---------------- 128x128 MFMA GEMM, BK=32, 2-phase double-buffer (T3 minimum) ------------
// LDS [2][128][32] per operand (32KB total -> ~5 blocks/CU). Per iter: STAGE(next) first,
// then ds_read+MFMA(cur), then ONE barrier (its implicit vmcnt(0) waits loads that had the
// whole compute phase in flight). mode 1: fused QKV (N=3072) with block-uniform out select.
__global__ __launch_bounds__(256) void gemm128(
    const __bf16* __restrict__ A, const __bf16* __restrict__ W,
    const float* __restrict__ b0, const float* __restrict__ b1, const float* __restrict__ b2,
    void* __restrict__ o0, void* __restrict__ o1, void* __restrict__ o2,
    int K, int mode)
{
    __shared__ __bf16 sA[2][128][32];
    __shared__ __bf16 sB[2][128][32];
    const int lane = threadIdx.x & 63, widx = threadIdx.x >> 6;
    const int wr = widx >> 1, wc = widx & 1;
    const int c = lane & 15, g = lane >> 4;
    const long m0 = (long)blockIdx.y * 128, n0 = (long)blockIdx.x * 128;
    const int srow = lane >> 2;       // staging row within 16-row group
    const int schunk = lane & 3;      // 16B chunk within 64B row

    auto STAGE = [&](int buf, int k0) {
#pragma unroll
        for (int it = 0; it < 2; ++it) {
            const int row = widx * 32 + it * 16 + srow;
            gload16(A + (m0 + row) * K + k0 + ((schunk ^ (row & 3)) << 3),
                    &sA[buf][widx * 32 + it * 16][0]);
            gload16(W + (n0 + row) * K + k0 + ((schunk ^ (row & 3)) << 3),
                    &sB[buf][widx * 32 + it * 16][0]);
        }
    };

    f32x4 acc[4][4] = {};

    STAGE(0, 0);
    __syncthreads();
    const int NK = K >> 5;
    for (int kt = 0; kt < NK; ++kt) {
        const int cur = kt & 1;
        if (kt + 1 < NK) STAGE(cur ^ 1, (kt + 1) << 5);   // issue-early: hides under MFMA

        bf16x8 af[4], bfr[4];
#pragma unroll
        for (int i = 0; i < 4; ++i) {
            const int ra = wr * 64 + i * 16 + c;
            af[i]  = *(const bf16x8*)((const char*)&sA[cur][ra][0] + ((g ^ (ra & 3)) << 4));
            const int rb = wc * 64 + i * 16 + c;
            bfr[i] = *(const bf16x8*)((const char*)&sB[cur][rb][0] + ((g ^ (rb & 3)) << 4));
        }
#pragma unroll
        for (int i = 0; i < 4; ++i)
#pragma unroll
            for (int j = 0; j < 4; ++j)
                acc[i][j] = __builtin_amdgcn_mfma_f32_16x16x32_bf16(af[i], bfr[j], acc[i][j], 0, 0, 0);
        __syncthreads();   // single barrier/iter: next-buf loads done, cur-buf reads done
    }

    // epilogue
    const float* bias; void* ob; int obf16;
    long ncl;
    if (mode == 1) {
        const int sel = (int)(n0 >> 10);
        bias = sel == 0 ? b0 : (sel == 1 ? b1 : b2);
        ob   = sel == 0 ? o0 : (sel == 1 ? o1 : o2);
        ncl  = n0 & 1023; obf16 = 1;
    } else {
        bias = b0; ob = o0; ncl = n0; obf16 = 0;
    }
#pragma unroll
    for (int i = 0; i < 4; ++i)
#pragma unroll
        for (int j = 0; j < 4; ++j) {
            const long col = ncl + wc * 64 + j * 16 + c;
            const float bv = bias[col];
#pragma unroll
            for (int r = 0; r < 4; ++r) {
                const long row = m0 + wr * 64 + i * 16 + g * 4 + r;
                const float v = acc[i][j][r] + bv;
                if (obf16) ((__bf16*)ob)[row * 1024 + col] = (__bf16)v;
                else       ((float*)ob)[row * 1024 + col] = v;
            }
        }
}

// ---------------- V transpose with baked fragment permutation ----------------
// Vt[h*64+d][sgg + o] = Vrow[sgg+kv][h*64+d],  o = hf*32 + g4*8 + hi*4 + r
// for kv = hf*32 + hi*16 + g4*4 + r. Makes the attention PV A-fragment a single
// contiguous bf16x8 read. One wave per 64x64 tile; 4 waves/block.
__global__ __launch_bounds__(256) void vtrans(const __bf16* __restrict__ Vrow,
                                              __bf16* __restrict__ Vt) {
    __shared__ __bf16 tl[4][64][80];   // pad 80: 160B row stride keeps b128 aligned
    const int lane = threadIdx.x & 63, w = threadIdx.x >> 6;
    const int tile = blockIdx.x * 4 + w;           // 0..2047
    const int h = tile & 15;
    const int sgg = (tile >> 4) << 6;
    const int r8 = lane >> 3, c8 = lane & 7;
#pragma unroll
    for (int it = 0; it < 8; ++it) {
        const int kv = it * 8 + r8;
        bf16x8 v = *(const bf16x8*)(Vrow + (long)(sgg + kv) * H_ + h * 64 + c8 * 8);
        *(bf16x8*)(&tl[w][kv][c8 * 8]) = v;
    }
    __syncthreads();
    const int d = lane;
#pragma unroll
    for (int hf = 0; hf < 2; ++hf)
#pragma unroll
        for (int hi = 0; hi < 2; ++hi)
#pragma unroll
            for (int g4 = 0; g4 < 4; ++g4) {
                const int kv = hf * 32 + hi * 16 + g4 * 4;
                const int o  = hf * 32 + g4 * 8 + hi * 4;
                bf16x4 t;
#pragma unroll
                for (int r = 0; r < 4; ++r) t[r] = tl[w][kv + r][d];
                *(bf16x4*)(Vt + (long)(h * 64 + d) * SG_ + sgg + o) = t;
            }
}

// ---------------- MFMA causal flash attention, 8 waves, shared staging ----------------
// Block = (pi, bh): waves 0-3 compute chunk pi, waves 4-7 chunk 15-pi, SHARING one
// double-buffered K/V staging (uniform NT = 32-2*pi iters). PV A-fragment is a single
// swizzled ds_read_b128 (vtrans-permuted Vt). Base-2 softmax (raw v_exp_f32), defer-max.
__global__ __launch_bounds__(512) void attn_mfma3(
    const __bf16* __restrict__ Q, const __bf16* __restrict__ Kg,
    const __bf16* __restrict__ Vt, __bf16* __restrict__ Ab)
{
    __shared__ char smem[38400];                      // staging 32KB | epilogue 36.9KB
    __bf16 (*ldsK)[64][64] = (__bf16 (*)[64][64])smem;            // [2][64][64]
    __bf16 (*ldsV)[64][64] = (__bf16 (*)[64][64])(smem + 16384);  // [2][64][64]

    const int lane = threadIdx.x & 63, widx = threadIdx.x >> 6;   // widx 0..7
    const int c = lane & 15, g = lane >> 4;
    const int bid = blockIdx.x;
    const int bh = bid & 63, pi = bid >> 6;           // pi in 0..7
    const int b = bh >> 4, h = bh & 15;
    const int chunk = (widx < 4) ? pi : (15 - pi);
    const int q0w = chunk * 128 + (widx & 3) * 32;

    const int sr8 = lane >> 3;
    const int sc8 = lane & 7;
    const float qscale = 0.125f * 1.4426950408889634f;

    // Q fragments [qi][hf], pre-scaled
    bf16x8 qf[2][2];
#pragma unroll
    for (int qi = 0; qi < 2; ++qi)
#pragma unroll
        for (int hf = 0; hf < 2; ++hf) {
            const long qa = ((long)(b * S_ + q0w + qi * 16 + c)) * H_ + h * HS_ + hf * 32 + g * 8;
            bf16x8 t = *reinterpret_cast<const bf16x8*>(Q + qa);
#pragma unroll
            for (int j = 0; j < 8; ++j) t[j] = (__bf16)(qscale * (float)t[j]);
            qf[qi][hf] = t;
        }

    f32x4 ot[4][2] = {};
    float m[2] = {-1e30f, -1e30f}, l[2] = {0.f, 0.f};
    const int NT = 32 - 2 * pi;       // covers long chunk exactly; short chunk guarded

    // each wave stages 8 rows of K and 8 rows of V^T per tile
    auto STAGEKV = [&](int buf, int kt) {
        const int row = widx * 8 + sr8;
        gload16(Kg + ((long)(b * S_ + kt + row)) * H_ + h * HS_ + ((sc8 ^ (row & 7)) << 3),
                &ldsK[buf][widx * 8][0]);
        gload16(Vt + ((long)(h * HS_ + row)) * SG_ + b * S_ + kt + ((sc8 ^ (row & 7)) << 3),
                &ldsV[buf][widx * 8][0]);
    };

    STAGEKV(0, 0);
    __syncthreads();

    for (int t = 0; t < NT; ++t) {
        const int cur = t & 1;
        if (t + 1 < NT) STAGEKV(cur ^ 1, (t + 1) * 64);
        const int kt = t * 64;

        if (kt <= q0w + 31) {
            // ---- QK^T ----
            f32x4 st[4][2] = {};
#pragma unroll
            for (int t4 = 0; t4 < 4; ++t4) {
                const int r = t4 * 16 + c;
                const char* kp = (const char*)&ldsK[cur][r][0];
                bf16x8 kf0 = *(const bf16x8*)(kp + (((g)     ^ (c & 7)) << 4));
                bf16x8 kf1 = *(const bf16x8*)(kp + (((4 | g) ^ (c & 7)) << 4));
#pragma unroll
                for (int qi = 0; qi < 2; ++qi) {
                    st[t4][qi] = __builtin_amdgcn_mfma_f32_16x16x32_bf16(kf0, qf[qi][0], st[t4][qi], 0, 0, 0);
                    st[t4][qi] = __builtin_amdgcn_mfma_f32_16x16x32_bf16(kf1, qf[qi][1], st[t4][qi], 0, 0, 0);
                }
            }
            // ---- causal mask (diagonal tiles only) ----
            if (kt + 63 > q0w) {
#pragma unroll
                for (int t4 = 0; t4 < 4; ++t4)
#pragma unroll
                    for (int qi = 0; qi < 2; ++qi)
#pragma unroll
                        for (int r = 0; r < 4; ++r)
                            if (kt + t4 * 16 + g * 4 + r > q0w + qi * 16 + c)
                                st[t4][qi][r] = -1e30f;
            }
            // ---- online softmax (base-2, defer-max, raw v_exp) ----
            bf16x8 pf[2][2];
            float fr[2];
            int resc = 0;
#pragma unroll
            for (int qi = 0; qi < 2; ++qi) {
                const float a0 = M3(st[0][qi][0], st[0][qi][1], st[0][qi][2]);
                const float a1 = M3(st[0][qi][3], st[1][qi][0], st[1][qi][1]);
                const float a2 = M3(st[1][qi][2], st[1][qi][3], st[2][qi][0]);
                const float a3 = M3(st[2][qi][1], st[2][qi][2], st[2][qi][3]);
                const float a4 = M3(st[3][qi][0], st[3][qi][1], st[3][qi][2]);
                float pm = M3(M3(a0, a1, a2), a3, fmaxf(a4, st[3][qi][3]));
                pm = fmaxf(pm, __shfl_xor(pm, 16));
                pm = fmaxf(pm, __shfl_xor(pm, 32));
                const int defer = __all(pm - m[qi] <= 8.0f);
                float mn;
                if (defer) {
                    mn = m[qi]; fr[qi] = 1.0f;
                } else {
                    mn = fmaxf(m[qi], pm);
                    fr[qi] = fexp2(m[qi] - mn);
                    m[qi] = mn;
                    resc = 1;
                }
                float p[16], rs = 0.f;
#pragma unroll
                for (int t4 = 0; t4 < 4; ++t4)
#pragma unroll
                    for (int r = 0; r < 4; ++r) {
                        const float e = fexp2(st[t4][qi][r] - mn);
                        p[t4 * 4 + r] = e; rs += e;
                    }
                rs += __shfl_xor(rs, 16);
                rs += __shfl_xor(rs, 32);
                l[qi] = l[qi] * fr[qi] + rs;
#pragma unroll
                for (int j = 0; j < 8; ++j) {
                    pf[0][qi][j] = (__bf16)p[j];
                    pf[1][qi][j] = (__bf16)p[8 + j];
                }
            }
            // ---- PV ----
            if (resc) {
#pragma unroll
                for (int blk = 0; blk < 4; ++blk) {
                    ot[blk][0] *= fr[0];
                    ot[blk][1] *= fr[1];
                }
            }
#pragma unroll
            for (int blk = 0; blk < 4; ++blk) {
                const char* vp = (const char*)&ldsV[cur][blk * 16 + c][0];
#pragma unroll
                for (int hf = 0; hf < 2; ++hf) {
                    bf16x8 vf = *(const bf16x8*)(vp + (((hf * 4 + g) ^ (c & 7)) << 4));
#pragma unroll
                    for (int qi = 0; qi < 2; ++qi)
                        ot[blk][qi] = __builtin_amdgcn_mfma_f32_16x16x32_bf16(vf, pf[hf][qi], ot[blk][qi], 0, 0, 0);
                }
            }
        }
        __syncthreads();
    }

    // ---- epilogue: per-wave region aliased over the (now-dead) staging LDS ----
    __bf16* myo = (__bf16*)smem + widx * (32 * 72);
#pragma unroll
    for (int qi = 0; qi < 2; ++qi) {
        const float invl = 1.0f / l[qi];
#pragma unroll
        for (int blk = 0; blk < 4; ++blk) {
            bf16x4 tv;
#pragma unroll
            for (int r = 0; r < 4; ++r) tv[r] = (__bf16)(ot[blk][qi][r] * invl);
            *reinterpret_cast<bf16x4*>(myo + (qi * 16 + c) * 72 + blk * 16 + g * 4) = tv;
        }
    }
#pragma unroll
    for (int half = 0; half < 2; ++half) {
        const int qr = lane >> 2, dc = (lane & 3) * 16;
        const __bf16* src = myo + (half * 16 + qr) * 72 + dc;
        bf16x8 r0 = *reinterpret_cast<const bf16x8*>(src);
        bf16x8 r1 = *reinterpret_cast<const bf16x8*>(src + 8);
        __bf16* dst = Ab + ((long)(b * S_ + q0w + half * 16 + qr)) * H_ + h * HS_ + dc;
        *reinterpret_cast<bf16x8*>(dst) = r0;
        *reinterpret_cast<bf16x8*>(dst + 8) = r1;
    }
}

// ---------------- launch ----------------
extern "C" void kernel_launch(void* const* d_in, const int* in_sizes, int n_in,
                              void* d_out, int out_size, void* d_ws, size_t ws_size,
                              hipStream_t stream) {
    const float* x  = (const float*)d_in[0];
    const float* Wq = (const float*)d_in[1];
    const float* bq = (const float*)d_in[2];
    const float* Wk = (const float*)d_in[3];
    const float* bk = (const float*)d_in[4];
    const float* Wv = (const float*)d_in[5];
    const float* bv = (const float*)d_in[6];
    const float* Wp = (const float*)d_in[7];
    const float* bp = (const float*)d_in[8];
    float* out = (float*)d_out;

    const int M = SG_;         // 8192
    const int K = H_;          // 1024

    char* ws = (char*)d_ws;
    size_t off = 0;
    __bf16* xb   = (__bf16*)(ws + off); off += (size_t)M * K * 2;     // 16MB; dead after QKV gemm
    __bf16* Wqb  = (__bf16*)(ws + off); off += (size_t)H_ * K * 2;    // Wq,Wk,Wv contiguous (fused N=3072)
    __bf16* Wkb  = (__bf16*)(ws + off); off += (size_t)H_ * K * 2;
    __bf16* Wvb  = (__bf16*)(ws + off); off += (size_t)H_ * K * 2;
    __bf16* Wpb  = (__bf16*)(ws + off); off += (size_t)H_ * K * 2;
    __bf16* Qb   = (__bf16*)(ws + off); off += (size_t)M * H_ * 2;
    __bf16* Kbf  = (__bf16*)(ws + off); off += (size_t)M * H_ * 2;
    __bf16* Vrow = (__bf16*)(ws + off); off += (size_t)M * H_ * 2;    // row-major V (+bias)
    __bf16* Ab   = (__bf16*)(ws + off); off += (size_t)M * H_ * 2;
    __bf16* Vt   = xb;                                                 // alias: permuted V^T [1024][8192]

    {
        int n4 = M * K / 4;
        cvt_f32_bf16<<<(n4 + 255) / 256, 256, 0, stream>>>(x, xb, n4);
        int w4 = H_ * K / 4;
        dim3 gw((w4 + 255) / 256, 4);
        cvt_w4<<<gw, 256, 0, stream>>>(Wq, Wk, Wv, Wp, Wqb, Wkb, Wvb, Wpb, w4);
    }

    // fused QKV projection: [8192 x 3072] = xb @ [Wq;Wk;Wv]^T, 1536 blocks (6/CU)
    {
        dim3 g(3 * H_ / 128, M / 128);
        gemm128<<<g, 256, 0, stream>>>(xb, Wqb, bq, bk, bv, Qb, Kbf, Vrow, K, 1);
    }

    // V transpose with fragment permutation (reads Vrow, writes Vt==xb after QKV gemm done)
    vtrans<<<512, 256, 0, stream>>>(Vrow, Vt);

    // attention: 512 blocks x 8 waves (paired chunks share staging)
    attn_mfma3<<<512, 512, 0, stream>>>(Qb, Kbf, Vt, Ab);

    // output projection -> fp32 d_out
    {
        dim3 g(H_ / 128, M / 128);
        gemm128<<<g, 256, 0, stream>>>(Ab, Wpb, bp, nullptr, nullptr, out, nullptr, nullptr, K, 0);
    }
}